// Round 3
// baseline (1238.413 us; speedup 1.0000x reference)
//
#include <hip/hip_runtime.h>
#include <hip/hip_bf16.h>

#define NPTS 100000
#define NK   1600000   // NPTS * 16

typedef __attribute__((ext_vector_type(8))) short bf16x8;
typedef __attribute__((ext_vector_type(4))) float f32x4;
typedef union { bf16x8 v; unsigned u[4]; } fragu;

#define MFMA(a,b,c) __builtin_amdgcn_mfma_f32_16x16x32_bf16((a),(b),(c),0,0,0)

// ws fragment-table offsets (in shorts). Layout per region: [(chunk*64+lane)*8+t]
#define WS_W01  0        // 3 chunks  (K=96: k0..63 = x@W01[3:], k64..66 = pr@W01[0:3], k67 = b01)
#define WS_WBIL 1536     // 8 chunks  (K=256: k=i*16+j -> Wbil[o][i][j])
#define WS_W2A  5632     // 4 ntiles  (K=32)
#define WS_W2B  7680     // 2 chunks  (K=64, cols 8..15 zero)
#define WS_WPE  8704     // 4 ntiles  (K=32: k0..2 = Wp2, k3 = bp2, rest 0)
#define WS_TOTAL_SHORTS 10752

__device__ inline unsigned cvtpk(float lo, float hi) {
  unsigned r;
  asm("v_cvt_pk_bf16_f32 %0, %1, %2" : "=v"(r) : "v"(lo), "v"(hi));
  return r;
}
__device__ inline short bfr(float f) {  // RNE f32->bf16 (finite inputs)
  unsigned u = __float_as_uint(f);
  u += 0x7fff + ((u >> 16) & 1);
  return (short)(u >> 16);
}

// ---------------------------------------------------------------------------
// Prep: pack weights into bf16 MFMA B-fragment tables (k-enum: k=(l>>4)*8+t)
// ---------------------------------------------------------------------------
__global__ __launch_bounds__(256) void k_prep(
    const float* __restrict__ W01, const float* __restrict__ b01,
    const float* __restrict__ Wbil,
    const float* __restrict__ W2a, const float* __restrict__ W2b,
    const float* __restrict__ Wp2, const float* __restrict__ bp2,
    short* __restrict__ ws)
{
  const int t = threadIdx.x;
  for (int i = t; i < 3 * 512; i += 256) {
    int tt = i & 7, l = (i >> 3) & 63, kc = i >> 9;
    int o = l & 15, k = kc * 32 + ((l >> 4) << 3) + tt;
    float v = 0.f;
    if (k < 64) v = W01[(3 + k) * 16 + o];
    else if (k < 67) v = W01[(k - 64) * 16 + o];
    else if (k == 67) v = b01[o];
    ws[WS_W01 + i] = bfr(v);
  }
  for (int i = t; i < 8 * 512; i += 256) {
    int tt = i & 7, l = (i >> 3) & 63, kc = i >> 9;
    int o = l & 15, k = kc * 32 + ((l >> 4) << 3) + tt;
    ws[WS_WBIL + i] = bfr(Wbil[o * 256 + k]);
  }
  for (int i = t; i < 4 * 512; i += 256) {
    int tt = i & 7, l = (i >> 3) & 63, nt = i >> 9;
    int c = nt * 16 + (l & 15), k = ((l >> 4) << 3) + tt;
    ws[WS_W2A + i] = bfr(W2a[k * 64 + c]);
  }
  for (int i = t; i < 2 * 512; i += 256) {
    int tt = i & 7, l = (i >> 3) & 63, kc = i >> 9;
    int m = l & 15, k = kc * 32 + ((l >> 4) << 3) + tt;
    ws[WS_W2B + i] = bfr(m < 8 ? W2b[k * 8 + m] : 0.f);
  }
  for (int i = t; i < 4 * 512; i += 256) {
    int tt = i & 7, l = (i >> 3) & 63, nt = i >> 9;
    int c = nt * 16 + (l & 15), k = ((l >> 4) << 3) + tt;
    float v = 0.f;
    if (k < 3) v = Wp2[k * 64 + c]; else if (k == 3) v = bp2[c];
    ws[WS_WPE + i] = bfr(v);
  }
}

// ---------------------------------------------------------------------------
// Kernel A: y = x @ W3 + b3
// ---------------------------------------------------------------------------
__global__ __launch_bounds__(256) void k_xw3(
    const float* __restrict__ x, const float* __restrict__ W3,
    const float* __restrict__ b3, float* __restrict__ y)
{
  int t = blockIdx.x * 256 + threadIdx.x;
  int i = __builtin_amdgcn_readfirstlane(t >> 6);
  int c = t & 63;
  if (i >= NPTS) return;
  const float* xr = x + i * 64;
  float acc = b3[c];
#pragma unroll
  for (int k = 0; k < 64; ++k)
    acc = fmaf(xr[k], W3[k * 64 + c], acc);
  y[i * 64 + c] = acc;
}

// ---------------------------------------------------------------------------
// Main: per-wave MFMA pipeline, 64 rows/wave, 4 waves/block.
// ---------------------------------------------------------------------------
__global__ __launch_bounds__(256) void k_main(
    const float* __restrict__ p, const float* __restrict__ x,
    const int* __restrict__ knn, const short* __restrict__ wsf,
    const float* __restrict__ Wp1, const float* __restrict__ bp1,
    const float* __restrict__ bnp_s, const float* __restrict__ bnp_b,
    const float* __restrict__ bbil,
    const float* __restrict__ bn2a_s, const float* __restrict__ bn2a_b,
    const float* __restrict__ bn2b_s, const float* __restrict__ bn2b_b,
    const float* __restrict__ W2c, const float* __restrict__ b2c,
    const float* __restrict__ Wp2, const float* __restrict__ bp2,
    const float* __restrict__ y,
    float* __restrict__ x_out, float* __restrict__ x_knn)
{
  // LDS pools (overlaid across barrier-separated stages). 62,464 B total.
  __shared__ __align__(16) char poolA[36864]; // e_lds f32[4][64][20] -> ha bf16[4][64][72]
  __shared__ __align__(16) char poolB[20480]; // ef bf16[4][64][40]   -> h2 f32[4][64][8]
  __shared__ int   idxw[4][64];
  __shared__ __align__(16) float prw[4][64][4];

  float (*e_lds)[64][20] = (float(*)[64][20])poolA;
  short (*ha_lds)[64][72] = (short(*)[64][72])poolA;
  short (*ef_lds)[64][40] = (short(*)[64][40])poolB;
  float (*h2_lds)[64][8]  = (float(*)[64][8])poolB;

  const int tid  = threadIdx.x;
  const int w    = tid >> 6;
  const int lane = tid & 63;
  const int mloc = lane & 15;
  const int kblk = lane >> 4;
  const int row  = blockIdx.x * 256 + tid;   // grid exact: no bounds check
  const int n    = row >> 4;
  const int j    = row & 15;
  const int idx  = knn[row];

  const float pr0 = p[idx * 3 + 0] - p[n * 3 + 0];
  const float pr1 = p[idx * 3 + 1] - p[n * 3 + 1];
  const float pr2 = p[idx * 3 + 2] - p[n * 3 + 2];

  // q = relu(bn(p_r @ Wp1 + bp1))
  float q0, q1, q2;
  {
    float v0 = bp1[0] + pr0 * Wp1[0] + pr1 * Wp1[3] + pr2 * Wp1[6];
    float v1 = bp1[1] + pr0 * Wp1[1] + pr1 * Wp1[4] + pr2 * Wp1[7];
    float v2 = bp1[2] + pr0 * Wp1[2] + pr1 * Wp1[5] + pr2 * Wp1[8];
    q0 = fmaxf(fmaf(v0, bnp_s[0], bnp_b[0]), 0.f);
    q1 = fmaxf(fmaf(v1, bnp_s[1], bnp_b[1]), 0.f);
    q2 = fmaxf(fmaf(v2, bnp_s[2], bnp_b[2]), 0.f);
  }

  // ---- S0: stage idx, pr, q (q hides in e_lds cols 16..19)
  idxw[w][lane] = idx;
  prw[w][lane][0] = pr0; prw[w][lane][1] = pr1; prw[w][lane][2] = pr2; prw[w][lane][3] = 1.f;
  *(float4*)&e_lds[w][lane][16] = make_float4(q0, q1, q2, 1.f);
  __syncthreads();   // B0

#define FR(off, idx_) (((const bf16x8*)wsf)[(off) / 8 + (idx_)])

  // ---- GEMM1: e = relu([x[idx] | pr | 1] @ W01ext), K=96
  {
    bf16x8 bw0 = FR(WS_W01, 0 * 64 + lane);
    bf16x8 bw1 = FR(WS_W01, 1 * 64 + lane);
    bf16x8 bw2 = FR(WS_W01, 2 * 64 + lane);
    const float4* x4 = (const float4*)x;
#pragma unroll 1
    for (int g = 0; g < 4; ++g) {
      int rl = g * 16 + mloc;
      int ridx = idxw[w][rl];
      f32x4 acc = {0.f, 0.f, 0.f, 0.f};
      {
        float4 xa = x4[ridx * 16 + kblk * 2];
        float4 xb = x4[ridx * 16 + kblk * 2 + 1];
        fragu A;
        A.u[0] = cvtpk(xa.x, xa.y); A.u[1] = cvtpk(xa.z, xa.w);
        A.u[2] = cvtpk(xb.x, xb.y); A.u[3] = cvtpk(xb.z, xb.w);
        acc = MFMA(A.v, bw0, acc);
      }
      {
        float4 xa = x4[ridx * 16 + 8 + kblk * 2];
        float4 xb = x4[ridx * 16 + 8 + kblk * 2 + 1];
        fragu A;
        A.u[0] = cvtpk(xa.x, xa.y); A.u[1] = cvtpk(xa.z, xa.w);
        A.u[2] = cvtpk(xb.x, xb.y); A.u[3] = cvtpk(xb.z, xb.w);
        acc = MFMA(A.v, bw1, acc);
      }
      {
        float4 pv = *(const float4*)&prw[w][rl][0];
        unsigned u0 = cvtpk(pv.x, pv.y), u1 = cvtpk(pv.z, pv.w);
        fragu A;
        A.u[0] = (kblk == 0) ? u0 : 0u;
        A.u[1] = (kblk == 0) ? u1 : 0u;
        A.u[2] = 0u; A.u[3] = 0u;
        acc = MFMA(A.v, bw2, acc);
      }
#pragma unroll
      for (int r = 0; r < 4; ++r)
        e_lds[w][g * 16 + kblk * 4 + r][mloc] = fmaxf(acc[r], 0.f);
    }
  }
  __syncthreads();   // B1

  // ---- Bilinear: e2 = G @ Wr + bbil, G[row][i*16+j] = e_i*e_j, K=256
  {
    bf16x8 wb[8];
#pragma unroll
    for (int kc = 0; kc < 8; ++kc) wb[kc] = FR(WS_WBIL, kc * 64 + lane);
    const float bbo = bbil[mloc];
    const int jh = (kblk & 1), ih = (kblk >> 1);
#pragma unroll 1
    for (int g = 0; g < 4; ++g) {
      int rl = g * 16 + mloc;
      float er[16];
      *(float4*)&er[0]  = *(const float4*)&e_lds[w][rl][0];
      *(float4*)&er[4]  = *(const float4*)&e_lds[w][rl][4];
      *(float4*)&er[8]  = *(const float4*)&e_lds[w][rl][8];
      *(float4*)&er[12] = *(const float4*)&e_lds[w][rl][12];
      float ej[8];
#pragma unroll
      for (int t = 0; t < 8; ++t) ej[t] = jh ? er[8 + t] : er[t];
      f32x4 acc = {0.f, 0.f, 0.f, 0.f};
#pragma unroll
      for (int kc = 0; kc < 8; ++kc) {
        float ei = ih ? er[kc * 2 + 1] : er[kc * 2];
        fragu A;
        A.u[0] = cvtpk(ei * ej[0], ei * ej[1]);
        A.u[1] = cvtpk(ei * ej[2], ei * ej[3]);
        A.u[2] = cvtpk(ei * ej[4], ei * ej[5]);
        A.u[3] = cvtpk(ei * ej[6], ei * ej[7]);
        acc = MFMA(A.v, wb[kc], acc);
      }
#pragma unroll
      for (int r = 0; r < 4; ++r)
        ef_lds[w][g * 16 + kblk * 4 + r][mloc] = bfr(acc[r] + bbo);
    }
  }

  // ---- pe-GEMM: pe = [q|1]@[Wp2;bp2] (K=32, k<4 valid); shrink = sum_a pe[a*16+b]
  {
    bf16x8 wp[4];
#pragma unroll
    for (int nt = 0; nt < 4; ++nt) wp[nt] = FR(WS_WPE, nt * 64 + lane);
#pragma unroll 1
    for (int g = 0; g < 4; ++g) {
      int rl = g * 16 + mloc;
      float4 qv = *(const float4*)&e_lds[w][rl][16];
      unsigned u0 = cvtpk(qv.x, qv.y), u1 = cvtpk(qv.z, qv.w);
      fragu A;
      A.u[0] = (kblk == 0) ? u0 : 0u;
      A.u[1] = (kblk == 0) ? u1 : 0u;
      A.u[2] = 0u; A.u[3] = 0u;
      f32x4 z = {0.f, 0.f, 0.f, 0.f};
      f32x4 p0 = MFMA(A.v, wp[0], z);
      f32x4 p1 = MFMA(A.v, wp[1], z);
      f32x4 p2 = MFMA(A.v, wp[2], z);
      f32x4 p3 = MFMA(A.v, wp[3], z);
#pragma unroll
      for (int r = 0; r < 4; ++r)
        ef_lds[w][g * 16 + kblk * 4 + r][16 + mloc] = bfr(p0[r] + p1[r] + p2[r] + p3[r]);
    }
  }
  __syncthreads();   // B2  (last e_lds read above -> ha may now overlay poolA)

  // ---- GEMM2: ha = relu(bn2a(ef @ W2a)), K=32, N=64 (4 ntiles)
  {
    bf16x8 wa0 = FR(WS_W2A, 0 * 64 + lane);
    bf16x8 wa1 = FR(WS_W2A, 1 * 64 + lane);
    bf16x8 wa2 = FR(WS_W2A, 2 * 64 + lane);
    bf16x8 wa3 = FR(WS_W2A, 3 * 64 + lane);
    float s0 = bn2a_s[mloc],      sb0 = bn2a_b[mloc];
    float s1 = bn2a_s[16 + mloc], sb1 = bn2a_b[16 + mloc];
    float s2 = bn2a_s[32 + mloc], sb2 = bn2a_b[32 + mloc];
    float s3 = bn2a_s[48 + mloc], sb3 = bn2a_b[48 + mloc];
#pragma unroll 1
    for (int g = 0; g < 4; ++g) {
      int rl = g * 16 + mloc;
      bf16x8 a = *(const bf16x8*)&ef_lds[w][rl][kblk * 8];
      f32x4 z = {0.f, 0.f, 0.f, 0.f};
      f32x4 c0 = MFMA(a, wa0, z);
      f32x4 c1 = MFMA(a, wa1, z);
      f32x4 c2 = MFMA(a, wa2, z);
      f32x4 c3 = MFMA(a, wa3, z);
#pragma unroll
      for (int r = 0; r < 4; ++r) {
        int rr = g * 16 + kblk * 4 + r;
        ha_lds[w][rr][mloc]      = bfr(fmaxf(fmaf(c0[r], s0, sb0), 0.f));
        ha_lds[w][rr][16 + mloc] = bfr(fmaxf(fmaf(c1[r], s1, sb1), 0.f));
        ha_lds[w][rr][32 + mloc] = bfr(fmaxf(fmaf(c2[r], s2, sb2), 0.f));
        ha_lds[w][rr][48 + mloc] = bfr(fmaxf(fmaf(c3[r], s3, sb3), 0.f));
      }
    }
  }
  __syncthreads();   // B3  (last ef read above -> h2 may now overlay poolB)

  // ---- GEMM3: h2 = relu(bn2b(ha @ W2b)), K=64, N=8
  {
    bf16x8 wb0 = FR(WS_W2B, 0 * 64 + lane);
    bf16x8 wb1 = FR(WS_W2B, 1 * 64 + lane);
    float ss = (mloc < 8) ? bn2b_s[mloc] : 0.f;
    float sb = (mloc < 8) ? bn2b_b[mloc] : 0.f;
#pragma unroll 1
    for (int g = 0; g < 4; ++g) {
      int rl = g * 16 + mloc;
      bf16x8 a0 = *(const bf16x8*)&ha_lds[w][rl][kblk * 8];
      bf16x8 a1 = *(const bf16x8*)&ha_lds[w][rl][32 + kblk * 8];
      f32x4 acc = {0.f, 0.f, 0.f, 0.f};
      acc = MFMA(a0, wb0, acc);
      acc = MFMA(a1, wb1, acc);
      if (mloc < 8) {
#pragma unroll
        for (int r = 0; r < 4; ++r)
          h2_lds[w][g * 16 + kblk * 4 + r][mloc] = fmaxf(fmaf(acc[r], ss, sb), 0.f);
      }
    }
  }
  __syncthreads();   // B4

  // ---- per-thread tail: W2c + softmax over 16 neighbors
  float h2r[8];
  *(float4*)&h2r[0] = *(const float4*)&h2_lds[w][lane][0];
  *(float4*)&h2r[4] = *(const float4*)&h2_lds[w][lane][4];
  float h3[8];
#pragma unroll
  for (int b = 0; b < 8; ++b) h3[b] = b2c[b];
#pragma unroll
  for (int m = 0; m < 8; ++m) {
    float r = h2r[m];
#pragma unroll
    for (int b = 0; b < 8; ++b) h3[b] = fmaf(r, W2c[m * 8 + b], h3[b]);
  }
  float wv[8];
#pragma unroll
  for (int b = 0; b < 8; ++b) {
    float mx = h3[b];
    mx = fmaxf(mx, __shfl_xor(mx, 1, 16));
    mx = fmaxf(mx, __shfl_xor(mx, 2, 16));
    mx = fmaxf(mx, __shfl_xor(mx, 4, 16));
    mx = fmaxf(mx, __shfl_xor(mx, 8, 16));
    float ex = __expf(h3[b] - mx);
    float s = ex;
    s += __shfl_xor(s, 1, 16);
    s += __shfl_xor(s, 2, 16);
    s += __shfl_xor(s, 4, 16);
    s += __shfl_xor(s, 8, 16);
    wv[b] = ex / s;
  }

  // ---- phase 2: x_knn = (y[idx] + pe) * w ; x_out = sum_k x_knn
  const float4* y4 = (const float4*)y;
  f32x4* xk4 = (f32x4*)(x_knn + (long long)row * 64);
  float xo[4] = {0.f, 0.f, 0.f, 0.f};
#pragma unroll
  for (int c0 = 0; c0 < 16; ++c0) {
    float4 yv = y4[idx * 16 + c0];
    float comp[4] = {yv.x, yv.y, yv.z, yv.w};
    float vals[4];
#pragma unroll
    for (int cc = 0; cc < 4; ++cc) {
      const int c = c0 * 4 + cc;
      float pe = bp2[c] + q0 * Wp2[c] + q1 * Wp2[64 + c] + q2 * Wp2[128 + c];
      float val = (comp[cc] + pe) * wv[c & 7];
      vals[cc] = val;
      float r = val;
      r += __shfl_xor(r, 1, 16);
      r += __shfl_xor(r, 2, 16);
      r += __shfl_xor(r, 4, 16);
      r += __shfl_xor(r, 8, 16);
      if (j == (c & 15)) xo[c >> 4] = r;
    }
    f32x4 st;
    st.x = vals[0]; st.y = vals[1]; st.z = vals[2]; st.w = vals[3];
    __builtin_nontemporal_store(st, &xk4[c0]);
  }
#pragma unroll
  for (int g = 0; g < 4; ++g)
    x_out[n * 64 + g * 16 + j] = xo[g];
}

// ---------------------------------------------------------------------------
// Kernel C: finalize tail outputs (knn_idx as float, p_r)
// ---------------------------------------------------------------------------
__global__ __launch_bounds__(256) void k_tail(
    const float* __restrict__ p, const int* __restrict__ knn,
    float* __restrict__ knn_f, float* __restrict__ p_r)
{
  int row = blockIdx.x * 256 + threadIdx.x;
  if (row >= NK) return;
  int n = row >> 4;
  int idx = knn[row];
  knn_f[row] = (float)idx;
  p_r[row * 3 + 0] = p[idx * 3 + 0] - p[n * 3 + 0];
  p_r[row * 3 + 1] = p[idx * 3 + 1] - p[n * 3 + 1];
  p_r[row * 3 + 2] = p[idx * 3 + 2] - p[n * 3 + 2];
}

// ---------------------------------------------------------------------------
extern "C" void kernel_launch(void* const* d_in, const int* in_sizes, int n_in,
                              void* d_out, int out_size, void* d_ws, size_t ws_size,
                              hipStream_t stream)
{
  const float* p    = (const float*)d_in[0];
  const float* x    = (const float*)d_in[1];
  const int*   knn  = (const int*)d_in[2];
  const float* W01  = (const float*)d_in[3];
  const float* b01  = (const float*)d_in[4];
  const float* Wbil = (const float*)d_in[5];
  const float* bbil = (const float*)d_in[6];
  const float* Wp1  = (const float*)d_in[7];
  const float* bp1  = (const float*)d_in[8];
  const float* bnps = (const float*)d_in[9];
  const float* bnpb = (const float*)d_in[10];
  const float* Wp2  = (const float*)d_in[11];
  const float* bp2  = (const float*)d_in[12];
  const float* W2a  = (const float*)d_in[13];
  const float* s2a  = (const float*)d_in[14];
  const float* b2a  = (const float*)d_in[15];
  const float* W2b  = (const float*)d_in[16];
  const float* s2b  = (const float*)d_in[17];
  const float* b2b  = (const float*)d_in[18];
  const float* W2c  = (const float*)d_in[19];
  const float* b2c  = (const float*)d_in[20];
  const float* W3   = (const float*)d_in[21];
  const float* b3   = (const float*)d_in[22];

  float* outF  = (float*)d_out;
  float* x_out = outF;                 // [N,64]
  float* x_knn = outF + 6400000;       // [N,16,64]
  float* knn_f = outF + 108800000;     // [N,16]
  float* p_r   = outF + 110400000;     // [N,16,3]
  float* y     = knn_f;                // reuse 6.4M-float tail for x@W3+b3
  short* wsf   = (short*)d_ws;         // 21.5 KB fragment tables

  k_prep<<<1, 256, 0, stream>>>(W01, b01, Wbil, W2a, W2b, Wp2, bp2, wsf);
  k_xw3<<<25000, 256, 0, stream>>>(x, W3, b3, y);
  k_main<<<6250, 256, 0, stream>>>(p, x, knn, wsf, Wp1, bp1, bnps, bnpb,
                                   bbil, s2a, b2a, s2b, b2b, W2c, b2c,
                                   Wp2, bp2, y, x_out, x_knn);
  k_tail<<<6250, 256, 0, stream>>>(p, knn, knn_f, p_r);
}

// Round 4
// 437.661 us; speedup vs baseline: 2.8296x; 2.8296x over previous
//
#include <hip/hip_runtime.h>

#define NPTS 100000
#define NK   1600000   // NPTS * 16

typedef __attribute__((ext_vector_type(8))) short bf16x8;
typedef __attribute__((ext_vector_type(4))) float f32x4;
typedef union { bf16x8 v; unsigned u[4]; } fragu;

#define MFMA(a,b,c) __builtin_amdgcn_mfma_f32_16x16x32_bf16((a),(b),(c),0,0,0)

// ws fragment-table offsets (in shorts). Layout per region: [(chunk*64+lane)*8+t]
#define WS_W01  0        // 3 chunks (K=96: k0..63=x@W01[3:], k64..66=pr, k67=b01)
#define WS_WBIL 1536     // 8 chunks (K=256: k=i*16+j -> Wbil[o][i][j])
#define WS_W2A  5632     // 4 ntiles (K=32)
#define WS_W2B  7680     // 2 chunks (K=64, cols 8..15 zero)
#define WS_WPE  8704     // 4 ntiles (K=32: k0..2=Wp2, k3=bp2, rest 0)

__device__ inline unsigned cvtpk(float lo, float hi) {
  unsigned r;
  asm("v_cvt_pk_bf16_f32 %0, %1, %2" : "=v"(r) : "v"(lo), "v"(hi));
  return r;
}
__device__ inline short bfr(float f) {  // RNE f32->bf16 (finite inputs)
  unsigned u = __float_as_uint(f);
  u += 0x7fff + ((u >> 16) & 1);
  return (short)(u >> 16);
}

// ---------------------------------------------------------------------------
__global__ __launch_bounds__(256) void k_prep(
    const float* __restrict__ W01, const float* __restrict__ b01,
    const float* __restrict__ Wbil,
    const float* __restrict__ W2a, const float* __restrict__ W2b,
    const float* __restrict__ Wp2, const float* __restrict__ bp2,
    short* __restrict__ ws)
{
  const int t = threadIdx.x;
  for (int i = t; i < 3 * 512; i += 256) {
    int tt = i & 7, l = (i >> 3) & 63, kc = i >> 9;
    int o = l & 15, k = kc * 32 + ((l >> 4) << 3) + tt;
    float v = 0.f;
    if (k < 64) v = W01[(3 + k) * 16 + o];
    else if (k < 67) v = W01[(k - 64) * 16 + o];
    else if (k == 67) v = b01[o];
    ws[WS_W01 + i] = bfr(v);
  }
  for (int i = t; i < 8 * 512; i += 256) {
    int tt = i & 7, l = (i >> 3) & 63, kc = i >> 9;
    int o = l & 15, k = kc * 32 + ((l >> 4) << 3) + tt;
    ws[WS_WBIL + i] = bfr(Wbil[o * 256 + k]);
  }
  for (int i = t; i < 4 * 512; i += 256) {
    int tt = i & 7, l = (i >> 3) & 63, nt = i >> 9;
    int c = nt * 16 + (l & 15), k = ((l >> 4) << 3) + tt;
    ws[WS_W2A + i] = bfr(W2a[k * 64 + c]);
  }
  for (int i = t; i < 2 * 512; i += 256) {
    int tt = i & 7, l = (i >> 3) & 63, kc = i >> 9;
    int m = l & 15, k = kc * 32 + ((l >> 4) << 3) + tt;
    ws[WS_W2B + i] = bfr(m < 8 ? W2b[k * 8 + m] : 0.f);
  }
  for (int i = t; i < 4 * 512; i += 256) {
    int tt = i & 7, l = (i >> 3) & 63, nt = i >> 9;
    int c = nt * 16 + (l & 15), k = ((l >> 4) << 3) + tt;
    float v = 0.f;
    if (k < 3) v = Wp2[k * 64 + c]; else if (k == 3) v = bp2[c];
    ws[WS_WPE + i] = bfr(v);
  }
}

// ---------------------------------------------------------------------------
__global__ __launch_bounds__(256) void k_xw3(
    const float* __restrict__ x, const float* __restrict__ W3,
    const float* __restrict__ b3, float* __restrict__ y)
{
  int t = blockIdx.x * 256 + threadIdx.x;
  int i = __builtin_amdgcn_readfirstlane(t >> 6);
  int c = t & 63;
  if (i >= NPTS) return;
  const float* xr = x + i * 64;
  float acc = b3[c];
#pragma unroll
  for (int k = 0; k < 64; ++k)
    acc = fmaf(xr[k], W3[k * 64 + c], acc);
  y[i * 64 + c] = acc;
}

// ---------------------------------------------------------------------------
// Main: per-wave MFMA pipeline, 64 rows/wave, 4 indep waves/block, NO barriers.
// Per-wave LDS = 10240 B: R1 [0,5120) = e f32[64][20] -> haBuf bf16[64][40]
//                                      -> h2 f32[64][12]
//                R2 [5120,10240) = ef bf16[64][40]
// ---------------------------------------------------------------------------
__global__ __launch_bounds__(256, 4) void k_main(
    const float* __restrict__ p, const float* __restrict__ x,
    const int* __restrict__ knn, const short* __restrict__ wsf,
    const float* __restrict__ Wp1, const float* __restrict__ bp1,
    const float* __restrict__ bnp_s, const float* __restrict__ bnp_b,
    const float* __restrict__ bbil,
    const float* __restrict__ bn2a_s, const float* __restrict__ bn2a_b,
    const float* __restrict__ bn2b_s, const float* __restrict__ bn2b_b,
    const float* __restrict__ W2c, const float* __restrict__ b2c,
    const float* __restrict__ Wp2, const float* __restrict__ bp2,
    const float* __restrict__ y,
    float* __restrict__ x_out, float* __restrict__ x_knn)
{
  __shared__ __align__(16) char POOL[40960];

  const int tid  = threadIdx.x;
  const int w    = tid >> 6;
  const int lane = tid & 63;
  const int mloc = lane & 15;
  const int kblk = lane >> 4;
  const int row  = blockIdx.x * 256 + tid;   // grid exact
  const int n    = row >> 4;
  const int j    = row & 15;
  const int idx  = knn[row];

  char* wbase = POOL + w * 10240;
  float* eF  = (float*)wbase;            // [64][20] f32
  short* haS = (short*)wbase;            // [64][40] bf16 (overlays e)
  float* h2F = (float*)wbase;            // [64][12] f32  (overlays haBuf)
  short* efS = (short*)(wbase + 5120);   // [64][40] bf16

  const float pr0 = p[idx * 3 + 0] - p[n * 3 + 0];
  const float pr1 = p[idx * 3 + 1] - p[n * 3 + 1];
  const float pr2 = p[idx * 3 + 2] - p[n * 3 + 2];

  // q = relu(bn(p_r @ Wp1 + bp1))
  float q0, q1, q2;
  {
    float v0 = bp1[0] + pr0 * Wp1[0] + pr1 * Wp1[3] + pr2 * Wp1[6];
    float v1 = bp1[1] + pr0 * Wp1[1] + pr1 * Wp1[4] + pr2 * Wp1[7];
    float v2 = bp1[2] + pr0 * Wp1[2] + pr1 * Wp1[5] + pr2 * Wp1[8];
    q0 = fmaxf(fmaf(v0, bnp_s[0], bnp_b[0]), 0.f);
    q1 = fmaxf(fmaf(v1, bnp_s[1], bnp_b[1]), 0.f);
    q2 = fmaxf(fmaf(v2, bnp_s[2], bnp_b[2]), 0.f);
  }

#define FR(off, idx_) (((const bf16x8*)wsf)[(off) / 8 + (idx_)])

  // ---- GEMM1: e = relu([x[idx] | pr | 1] @ W01ext), K=96
  {
    bf16x8 bw0 = FR(WS_W01, 0 * 64 + lane);
    bf16x8 bw1 = FR(WS_W01, 1 * 64 + lane);
    bf16x8 bw2 = FR(WS_W01, 2 * 64 + lane);
    const float4* x4 = (const float4*)x;
#pragma unroll
    for (int g = 0; g < 4; ++g) {
      const int src = g * 16 + mloc;
      int   ridx = __shfl(idx, src, 64);
      float p0s  = __shfl(pr0, src, 64);
      float p1s  = __shfl(pr1, src, 64);
      float p2s  = __shfl(pr2, src, 64);
      f32x4 acc = {0.f, 0.f, 0.f, 0.f};
      {
        float4 xa = x4[ridx * 16 + kblk * 2];
        float4 xb = x4[ridx * 16 + kblk * 2 + 1];
        fragu A;
        A.u[0] = cvtpk(xa.x, xa.y); A.u[1] = cvtpk(xa.z, xa.w);
        A.u[2] = cvtpk(xb.x, xb.y); A.u[3] = cvtpk(xb.z, xb.w);
        acc = MFMA(A.v, bw0, acc);
      }
      {
        float4 xa = x4[ridx * 16 + 8 + kblk * 2];
        float4 xb = x4[ridx * 16 + 9 + kblk * 2];
        fragu A;
        A.u[0] = cvtpk(xa.x, xa.y); A.u[1] = cvtpk(xa.z, xa.w);
        A.u[2] = cvtpk(xb.x, xb.y); A.u[3] = cvtpk(xb.z, xb.w);
        acc = MFMA(A.v, bw1, acc);
      }
      {
        fragu A;
        A.u[0] = (kblk == 0) ? cvtpk(p0s, p1s) : 0u;
        A.u[1] = (kblk == 0) ? cvtpk(p2s, 1.f) : 0u;
        A.u[2] = 0u; A.u[3] = 0u;
        acc = MFMA(A.v, bw2, acc);
      }
#pragma unroll
      for (int r = 0; r < 4; ++r)
        eF[(g * 16 + kblk * 4 + r) * 20 + mloc] = fmaxf(acc[r], 0.f);
    }
  }

  // ---- Bilinear: e2 = G @ Wbil + bbil, G[row][i*16+j] = e_i*e_j, K=256
  {
    const float bbo = bbil[mloc];
    const int jh = (kblk & 1), ih = (kblk >> 1);
#pragma unroll 1
    for (int g = 0; g < 4; ++g) {
      const int rl = g * 16 + mloc;
      float er[16];
      *(float4*)&er[0]  = *(const float4*)&eF[rl * 20 + 0];
      *(float4*)&er[4]  = *(const float4*)&eF[rl * 20 + 4];
      *(float4*)&er[8]  = *(const float4*)&eF[rl * 20 + 8];
      *(float4*)&er[12] = *(const float4*)&eF[rl * 20 + 12];
      float ej[8];
#pragma unroll
      for (int t = 0; t < 8; ++t) ej[t] = jh ? er[8 + t] : er[t];
      f32x4 acc = {0.f, 0.f, 0.f, 0.f};
#pragma unroll
      for (int kc = 0; kc < 8; ++kc) {
        bf16x8 wb = FR(WS_WBIL, kc * 64 + lane);
        float ei = ih ? er[kc * 2 + 1] : er[kc * 2];
        fragu A;
        A.u[0] = cvtpk(ei * ej[0], ei * ej[1]);
        A.u[1] = cvtpk(ei * ej[2], ei * ej[3]);
        A.u[2] = cvtpk(ei * ej[4], ei * ej[5]);
        A.u[3] = cvtpk(ei * ej[6], ei * ej[7]);
        acc = MFMA(A.v, wb, acc);
      }
#pragma unroll
      for (int r = 0; r < 4; ++r)
        efS[(g * 16 + kblk * 4 + r) * 40 + mloc] = bfr(acc[r] + bbo);
    }
  }

  // ---- pe-GEMM: shrink = sum_a ([q|1]@[Wp2;bp2])[a*16+b] -> ef cols 16..31
  {
    bf16x8 wp0 = FR(WS_WPE, 0 * 64 + lane);
    bf16x8 wp1 = FR(WS_WPE, 1 * 64 + lane);
    bf16x8 wp2f = FR(WS_WPE, 2 * 64 + lane);
    bf16x8 wp3 = FR(WS_WPE, 3 * 64 + lane);
#pragma unroll 1
    for (int g = 0; g < 4; ++g) {
      const int src = g * 16 + mloc;
      float q0s = __shfl(q0, src, 64);
      float q1s = __shfl(q1, src, 64);
      float q2s = __shfl(q2, src, 64);
      fragu A;
      A.u[0] = (kblk == 0) ? cvtpk(q0s, q1s) : 0u;
      A.u[1] = (kblk == 0) ? cvtpk(q2s, 1.f) : 0u;
      A.u[2] = 0u; A.u[3] = 0u;
      f32x4 z = {0.f, 0.f, 0.f, 0.f};
      f32x4 s0 = MFMA(A.v, wp0, z);
      f32x4 s1 = MFMA(A.v, wp1, z);
      f32x4 s2 = MFMA(A.v, wp2f, z);
      f32x4 s3 = MFMA(A.v, wp3, z);
#pragma unroll
      for (int r = 0; r < 4; ++r)
        efS[(g * 16 + kblk * 4 + r) * 40 + 16 + mloc] = bfr(s0[r] + s1[r] + s2[r] + s3[r]);
    }
  }

  // ---- GEMM2/GEMM3 in two col-halves through haBuf (overlays dead e).
  f32x4 h2acc[4];
#pragma unroll
  for (int g = 0; g < 4; ++g) h2acc[g] = (f32x4){0.f, 0.f, 0.f, 0.f};

#pragma unroll
  for (int half = 0; half < 2; ++half) {
    bf16x8 wa0 = FR(WS_W2A, (half * 2 + 0) * 64 + lane);
    bf16x8 wa1 = FR(WS_W2A, (half * 2 + 1) * 64 + lane);
    float sA = bn2a_s[half * 32 + mloc],      bA = bn2a_b[half * 32 + mloc];
    float sB = bn2a_s[half * 32 + 16 + mloc], bB = bn2a_b[half * 32 + 16 + mloc];
    // GEMM2 half: ha cols [half*32, half*32+32) -> haBuf
#pragma unroll
    for (int g = 0; g < 4; ++g) {
      const int rl = g * 16 + mloc;
      bf16x8 a = *(const bf16x8*)&efS[rl * 40 + kblk * 8];
      f32x4 z = {0.f, 0.f, 0.f, 0.f};
      f32x4 c0 = MFMA(a, wa0, z);
      f32x4 c1 = MFMA(a, wa1, z);
#pragma unroll
      for (int r = 0; r < 4; ++r) {
        const int rr = g * 16 + kblk * 4 + r;
        haS[rr * 40 + mloc]      = bfr(fmaxf(fmaf(c0[r], sA, bA), 0.f));
        haS[rr * 40 + 16 + mloc] = bfr(fmaxf(fmaf(c1[r], sB, bB), 0.f));
      }
    }
    // GEMM3 half: h2 += haBuf @ W2b[half-chunk]
    bf16x8 wbh = FR(WS_W2B, half * 64 + lane);
#pragma unroll
    for (int g = 0; g < 4; ++g) {
      const int rl = g * 16 + mloc;
      bf16x8 a = *(const bf16x8*)&haS[rl * 40 + kblk * 8];
      h2acc[g] = MFMA(a, wbh, h2acc[g]);
    }
  }

  // ---- bn2b + relu -> h2F (overlays haBuf; all reads retired in-order)
  if (mloc < 8) {
    float ss = bn2b_s[mloc], sb = bn2b_b[mloc];
#pragma unroll
    for (int g = 0; g < 4; ++g)
#pragma unroll
      for (int r = 0; r < 4; ++r)
        h2F[(g * 16 + kblk * 4 + r) * 12 + mloc] =
            fmaxf(fmaf(h2acc[g][r], ss, sb), 0.f);
  }

  // ---- per-thread tail: W2c + softmax over 16 neighbors
  float h2r[8];
  *(float4*)&h2r[0] = *(const float4*)&h2F[lane * 12 + 0];
  *(float4*)&h2r[4] = *(const float4*)&h2F[lane * 12 + 4];
  float h3[8];
#pragma unroll
  for (int b = 0; b < 8; ++b) h3[b] = b2c[b];
#pragma unroll
  for (int m = 0; m < 8; ++m) {
    float r = h2r[m];
#pragma unroll
    for (int b = 0; b < 8; ++b) h3[b] = fmaf(r, W2c[m * 8 + b], h3[b]);
  }
  float wv[8];
#pragma unroll
  for (int b = 0; b < 8; ++b) {
    float mx = h3[b];
    mx = fmaxf(mx, __shfl_xor(mx, 1, 16));
    mx = fmaxf(mx, __shfl_xor(mx, 2, 16));
    mx = fmaxf(mx, __shfl_xor(mx, 4, 16));
    mx = fmaxf(mx, __shfl_xor(mx, 8, 16));
    float ex = __expf(h3[b] - mx);
    float s = ex;
    s += __shfl_xor(s, 1, 16);
    s += __shfl_xor(s, 2, 16);
    s += __shfl_xor(s, 4, 16);
    s += __shfl_xor(s, 8, 16);
    wv[b] = ex / s;
  }

  // ---- phase 2: x_knn = (y[idx] + pe) * w ; x_out = sum_j x_knn
  const float4* y4 = (const float4*)y;
  float* xkrow = x_knn + (long long)row * 64;
  float xo[4] = {0.f, 0.f, 0.f, 0.f};
#pragma unroll
  for (int h = 0; h < 2; ++h) {
    float4 yv[8];
#pragma unroll
    for (int u = 0; u < 8; ++u) yv[u] = y4[idx * 16 + h * 8 + u];
    f32x4 vout[8];
#pragma unroll
    for (int u = 0; u < 8; ++u) {
      float comp[4] = {yv[u].x, yv[u].y, yv[u].z, yv[u].w};
#pragma unroll
      for (int cc = 0; cc < 4; ++cc) {
        const int c = h * 32 + u * 4 + cc;
        float pe = bp2[c] + q0 * Wp2[c] + q1 * Wp2[64 + c] + q2 * Wp2[128 + c];
        float val = (comp[cc] + pe) * wv[c & 7];
        vout[u][cc] = val;
        float r = val;
        r += __shfl_xor(r, 1, 16);
        r += __shfl_xor(r, 2, 16);
        r += __shfl_xor(r, 4, 16);
        r += __shfl_xor(r, 8, 16);
        if (j == (c & 15)) xo[c >> 4] = r;
      }
    }
    // back-to-back stores covering one full 128B line
#pragma unroll
    for (int u = 0; u < 8; ++u)
      *(f32x4*)(xkrow + h * 32 + u * 4) = vout[u];
  }
#pragma unroll
  for (int g = 0; g < 4; ++g)
    x_out[n * 64 + g * 16 + j] = xo[g];
}

// ---------------------------------------------------------------------------
__global__ __launch_bounds__(256) void k_tail(
    const float* __restrict__ p, const int* __restrict__ knn,
    float* __restrict__ knn_f, float* __restrict__ p_r)
{
  int row = blockIdx.x * 256 + threadIdx.x;
  if (row >= NK) return;
  int n = row >> 4;
  int idx = knn[row];
  knn_f[row] = (float)idx;
  p_r[row * 3 + 0] = p[idx * 3 + 0] - p[n * 3 + 0];
  p_r[row * 3 + 1] = p[idx * 3 + 1] - p[n * 3 + 1];
  p_r[row * 3 + 2] = p[idx * 3 + 2] - p[n * 3 + 2];
}

// ---------------------------------------------------------------------------
extern "C" void kernel_launch(void* const* d_in, const int* in_sizes, int n_in,
                              void* d_out, int out_size, void* d_ws, size_t ws_size,
                              hipStream_t stream)
{
  const float* p    = (const float*)d_in[0];
  const float* x    = (const float*)d_in[1];
  const int*   knn  = (const int*)d_in[2];
  const float* W01  = (const float*)d_in[3];
  const float* b01  = (const float*)d_in[4];
  const float* Wbil = (const float*)d_in[5];
  const float* bbil = (const float*)d_in[6];
  const float* Wp1  = (const float*)d_in[7];
  const float* bp1  = (const float*)d_in[8];
  const float* bnps = (const float*)d_in[9];
  const float* bnpb = (const float*)d_in[10];
  const float* Wp2  = (const float*)d_in[11];
  const float* bp2  = (const float*)d_in[12];
  const float* W2a  = (const float*)d_in[13];
  const float* s2a  = (const float*)d_in[14];
  const float* b2a  = (const float*)d_in[15];
  const float* W2b  = (const float*)d_in[16];
  const float* s2b  = (const float*)d_in[17];
  const float* b2b  = (const float*)d_in[18];
  const float* W2c  = (const float*)d_in[19];
  const float* b2c  = (const float*)d_in[20];
  const float* W3   = (const float*)d_in[21];
  const float* b3   = (const float*)d_in[22];

  float* outF  = (float*)d_out;
  float* x_out = outF;                 // [N,64]
  float* x_knn = outF + 6400000;       // [N,16,64]
  float* knn_f = outF + 108800000;     // [N,16]
  float* p_r   = outF + 110400000;     // [N,16,3]
  float* y     = knn_f;                // reuse tail for x@W3+b3
  short* wsf   = (short*)d_ws;

  k_prep<<<1, 256, 0, stream>>>(W01, b01, Wbil, W2a, W2b, Wp2, bp2, wsf);
  k_xw3<<<25000, 256, 0, stream>>>(x, W3, b3, y);
  k_main<<<6250, 256, 0, stream>>>(p, x, knn, wsf, Wp1, bp1, bnps, bnpb,
                                   bbil, s2a, b2a, s2b, b2b, W2c, b2c,
                                   Wp2, bp2, y, x_out, x_knn);
  k_tail<<<6250, 256, 0, stream>>>(p, knn, knn_f, p_r);
}

// Round 5
// 417.209 us; speedup vs baseline: 2.9683x; 1.0490x over previous
//
#include <hip/hip_runtime.h>

#define NPTS 100000
#define NK   1600000   // NPTS * 16

typedef __attribute__((ext_vector_type(8))) short bf16x8;
typedef __attribute__((ext_vector_type(4))) float f32x4;
typedef union { bf16x8 v; unsigned u[4]; } fragu;

#define MFMA(a,b,c) __builtin_amdgcn_mfma_f32_16x16x32_bf16((a),(b),(c),0,0,0)

// ws fragment-table offsets (in shorts). Layout per region: [(chunk*64+lane)*8+t]
// NOTE: with the transposed chain these same tables now serve as A-fragments
// of W^T (A-frag of W^T == B-frag of W under the shared k-enumeration).
#define WS_W01  0        // 3 chunks (K=96: k0..63=x@W01[3:], k64..66=pr, k67=b01)
#define WS_WBIL 1536     // 8 chunks (K=256: k=i*16+j -> Wbil[o][i][j])
#define WS_W2A  5632     // 4 ntiles (K=32)
#define WS_W2B  7680     // 2 chunks (K=64, cols 8..15 zero)
#define WS_WPE  8704     // 4 ntiles (K=32: k0..2=Wp2, k3=bp2, rest 0)
#define WS_BYTES 21504

__device__ inline unsigned cvtpk(float lo, float hi) {
  unsigned r;
  asm("v_cvt_pk_bf16_f32 %0, %1, %2" : "=v"(r) : "v"(lo), "v"(hi));
  return r;
}
__device__ inline short bfr(float f) {  // RNE f32->bf16 (finite inputs)
  unsigned u = __float_as_uint(f);
  u += 0x7fff + ((u >> 16) & 1);
  return (short)(u >> 16);
}
__device__ inline float bflo(unsigned u) { return __uint_as_float(u << 16); }
__device__ inline float bfhi(unsigned u) { return __uint_as_float(u & 0xffff0000u); }

// ---------------------------------------------------------------------------
__global__ __launch_bounds__(256) void k_prep(
    const float* __restrict__ W01, const float* __restrict__ b01,
    const float* __restrict__ Wbil,
    const float* __restrict__ W2a, const float* __restrict__ W2b,
    const float* __restrict__ Wp2, const float* __restrict__ bp2,
    short* __restrict__ ws)
{
  const int t = threadIdx.x;
  for (int i = t; i < 3 * 512; i += 256) {
    int tt = i & 7, l = (i >> 3) & 63, kc = i >> 9;
    int o = l & 15, k = kc * 32 + ((l >> 4) << 3) + tt;
    float v = 0.f;
    if (k < 64) v = W01[(3 + k) * 16 + o];
    else if (k < 67) v = W01[(k - 64) * 16 + o];
    else if (k == 67) v = b01[o];
    ws[WS_W01 + i] = bfr(v);
  }
  for (int i = t; i < 8 * 512; i += 256) {
    int tt = i & 7, l = (i >> 3) & 63, kc = i >> 9;
    int o = l & 15, k = kc * 32 + ((l >> 4) << 3) + tt;
    ws[WS_WBIL + i] = bfr(Wbil[o * 256 + k]);
  }
  for (int i = t; i < 4 * 512; i += 256) {
    int tt = i & 7, l = (i >> 3) & 63, nt = i >> 9;
    int c = nt * 16 + (l & 15), k = ((l >> 4) << 3) + tt;
    ws[WS_W2A + i] = bfr(W2a[k * 64 + c]);
  }
  for (int i = t; i < 2 * 512; i += 256) {
    int tt = i & 7, l = (i >> 3) & 63, kc = i >> 9;
    int m = l & 15, k = kc * 32 + ((l >> 4) << 3) + tt;
    ws[WS_W2B + i] = bfr(m < 8 ? W2b[k * 8 + m] : 0.f);
  }
  for (int i = t; i < 4 * 512; i += 256) {
    int tt = i & 7, l = (i >> 3) & 63, nt = i >> 9;
    int c = nt * 16 + (l & 15), k = ((l >> 4) << 3) + tt;
    float v = 0.f;
    if (k < 3) v = Wp2[k * 64 + c]; else if (k == 3) v = bp2[c];
    ws[WS_WPE + i] = bfr(v);
  }
}

// ---------------------------------------------------------------------------
__global__ __launch_bounds__(256) void k_xw3(
    const float* __restrict__ x, const float* __restrict__ W3,
    const float* __restrict__ b3, float* __restrict__ y)
{
  int t = blockIdx.x * 256 + threadIdx.x;
  int i = __builtin_amdgcn_readfirstlane(t >> 6);
  int c = t & 63;
  if (i >= NPTS) return;
  const float* xr = x + i * 64;
  float acc = b3[c];
#pragma unroll
  for (int k = 0; k < 64; ++k)
    acc = fmaf(xr[k], W3[k * 64 + c], acc);
  y[i * 64 + c] = acc;
}

// ---------------------------------------------------------------------------
// Main: fully register-resident transposed MFMA chain. ZERO LDS.
// Wave = 64 rows = 4 points (tiles g); tile g: cols = neighbors j, rows = chans.
// Stage outputs (C-layout: chan = kblk*4+r, neighbor = mloc) are re-fragmented
// for the next stage's B-operand with __shfl only.
// ---------------------------------------------------------------------------
__global__ __launch_bounds__(256, 5) void k_main(
    const float* __restrict__ p, const float* __restrict__ x,
    const int* __restrict__ knn, const short* __restrict__ wsf,
    const float* __restrict__ Wp1, const float* __restrict__ bp1,
    const float* __restrict__ bnp_s, const float* __restrict__ bnp_b,
    const float* __restrict__ bbil,
    const float* __restrict__ bn2a_s, const float* __restrict__ bn2a_b,
    const float* __restrict__ bn2b_s, const float* __restrict__ bn2b_b,
    const float* __restrict__ W2c, const float* __restrict__ b2c,
    const float* __restrict__ Wp2, const float* __restrict__ bp2,
    const float* __restrict__ y,
    float* __restrict__ x_out, float* __restrict__ x_knn,
    float* __restrict__ knn_f, float* __restrict__ p_r)   // may be null
{
  const int tid  = threadIdx.x;
  const int lane = tid & 63;
  const int mloc = lane & 15;
  const int kblk = lane >> 4;
  const int row  = blockIdx.x * 256 + tid;   // grid exact
  const int n    = row >> 4;
  const int j    = row & 15;
  const int idx  = knn[row];

  const float pr0 = p[idx * 3 + 0] - p[n * 3 + 0];
  const float pr1 = p[idx * 3 + 1] - p[n * 3 + 1];
  const float pr2 = p[idx * 3 + 2] - p[n * 3 + 2];

  // q = relu(bn(p_r @ Wp1 + bp1))
  float q0, q1, q2;
  {
    float v0 = bp1[0] + pr0 * Wp1[0] + pr1 * Wp1[3] + pr2 * Wp1[6];
    float v1 = bp1[1] + pr0 * Wp1[1] + pr1 * Wp1[4] + pr2 * Wp1[7];
    float v2 = bp1[2] + pr0 * Wp1[2] + pr1 * Wp1[5] + pr2 * Wp1[8];
    q0 = fmaxf(fmaf(v0, bnp_s[0], bnp_b[0]), 0.f);
    q1 = fmaxf(fmaf(v1, bnp_s[1], bnp_b[1]), 0.f);
    q2 = fmaxf(fmaf(v2, bnp_s[2], bnp_b[2]), 0.f);
  }

#define FR(off, idx_) (((const bf16x8*)wsf)[(off) / 8 + (idx_)])

  // ---- GEMM1^T: eT[chan][j] per tile g; lane holds chans kblk*4..+4 of
  //      neighbor mloc, packed bf16. (A = W01ext table, B = gathered x rows.)
  unsigned epk[4][2];
  {
    bf16x8 bw0 = FR(WS_W01, 0 * 64 + lane);
    bf16x8 bw1 = FR(WS_W01, 1 * 64 + lane);
    bf16x8 bw2 = FR(WS_W01, 2 * 64 + lane);
    const float4* x4 = (const float4*)x;
#pragma unroll
    for (int g = 0; g < 4; ++g) {
      const int src = g * 16 + mloc;
      int   ridx = __shfl(idx, src, 64);
      float p0s  = __shfl(pr0, src, 64);
      float p1s  = __shfl(pr1, src, 64);
      float p2s  = __shfl(pr2, src, 64);
      f32x4 acc = {0.f, 0.f, 0.f, 0.f};
      {
        float4 xa = x4[ridx * 16 + kblk * 2];
        float4 xb = x4[ridx * 16 + kblk * 2 + 1];
        fragu B;
        B.u[0] = cvtpk(xa.x, xa.y); B.u[1] = cvtpk(xa.z, xa.w);
        B.u[2] = cvtpk(xb.x, xb.y); B.u[3] = cvtpk(xb.z, xb.w);
        acc = MFMA(bw0, B.v, acc);
      }
      {
        float4 xa = x4[ridx * 16 + 8 + kblk * 2];
        float4 xb = x4[ridx * 16 + 9 + kblk * 2];
        fragu B;
        B.u[0] = cvtpk(xa.x, xa.y); B.u[1] = cvtpk(xa.z, xa.w);
        B.u[2] = cvtpk(xb.x, xb.y); B.u[3] = cvtpk(xb.z, xb.w);
        acc = MFMA(bw1, B.v, acc);
      }
      {
        fragu B;
        B.u[0] = (kblk == 0) ? cvtpk(p0s, p1s) : 0u;
        B.u[1] = (kblk == 0) ? cvtpk(p2s, 1.f) : 0u;
        B.u[2] = 0u; B.u[3] = 0u;
        acc = MFMA(bw2, B.v, acc);
      }
      epk[g][0] = cvtpk(fmaxf(acc[0], 0.f), fmaxf(acc[1], 0.f));
      epk[g][1] = cvtpk(fmaxf(acc[2], 0.f), fmaxf(acc[3], 0.f));
    }
  }

  // ---- per-tile mid chain: bilinear^T, pe^T, GEMM2^T, GEMM3^T
  unsigned h2p[4][2];
#pragma unroll
  for (int g = 0; g < 4; ++g) {
    // gather full e-row (16 chans) of neighbor mloc
    float er[16];
    {
      unsigned a0 = __shfl(epk[g][0], mloc, 64);
      unsigned a1 = __shfl(epk[g][1], mloc, 64);
      unsigned b0 = __shfl(epk[g][0], mloc + 16, 64);
      unsigned b1 = __shfl(epk[g][1], mloc + 16, 64);
      unsigned c0 = __shfl(epk[g][0], mloc + 32, 64);
      unsigned c1 = __shfl(epk[g][1], mloc + 32, 64);
      unsigned d0 = __shfl(epk[g][0], mloc + 48, 64);
      unsigned d1 = __shfl(epk[g][1], mloc + 48, 64);
      er[0] = bflo(a0);  er[1] = bfhi(a0);  er[2]  = bflo(a1); er[3]  = bfhi(a1);
      er[4] = bflo(b0);  er[5] = bfhi(b0);  er[6]  = bflo(b1); er[7]  = bfhi(b1);
      er[8] = bflo(c0);  er[9] = bfhi(c0);  er[10] = bflo(c1); er[11] = bfhi(c1);
      er[12] = bflo(d0); er[13] = bfhi(d0); er[14] = bflo(d1); er[15] = bfhi(d1);
    }
    // Bilinear^T: lane supplies G[j][k]=e_i*e_jj, k=kc*32+kblk*8+t
    const int jhsel = kblk & 1, ihsel = kblk >> 1;
    float ej[8];
#pragma unroll
    for (int t = 0; t < 8; ++t) ej[t] = jhsel ? er[8 + t] : er[t];
    f32x4 acc2;
    {
      f32x4 bb = *(const f32x4*)&bbil[kblk * 4];
      acc2 = bb;   // fold bias in as C-init
#pragma unroll
      for (int kc = 0; kc < 8; ++kc) {
        bf16x8 wb = FR(WS_WBIL, kc * 64 + lane);
        float ei = ihsel ? er[2 * kc + 1] : er[2 * kc];
        fragu B;
        B.u[0] = cvtpk(ei * ej[0], ei * ej[1]);
        B.u[1] = cvtpk(ei * ej[2], ei * ej[3]);
        B.u[2] = cvtpk(ei * ej[4], ei * ej[5]);
        B.u[3] = cvtpk(ei * ej[6], ei * ej[7]);
        acc2 = MFMA(wb, B.v, acc2);
      }
    }
    // pe^T -> shrink: lane holds shrink chans kblk*4..+4 of neighbor mloc
    f32x4 shq;
    {
      const int src = g * 16 + mloc;
      float q0s = __shfl(q0, src, 64);
      float q1s = __shfl(q1, src, 64);
      float q2s = __shfl(q2, src, 64);
      fragu B;
      B.u[0] = (kblk == 0) ? cvtpk(q0s, q1s) : 0u;
      B.u[1] = (kblk == 0) ? cvtpk(q2s, 1.f) : 0u;
      B.u[2] = 0u; B.u[3] = 0u;
      f32x4 z = {0.f, 0.f, 0.f, 0.f};
      f32x4 s0 = MFMA(FR(WS_WPE, 0 * 64 + lane), B.v, z);
      f32x4 s1 = MFMA(FR(WS_WPE, 1 * 64 + lane), B.v, z);
      f32x4 s2 = MFMA(FR(WS_WPE, 2 * 64 + lane), B.v, z);
      f32x4 s3 = MFMA(FR(WS_WPE, 3 * 64 + lane), B.v, z);
#pragma unroll
      for (int r = 0; r < 4; ++r) shq[r] = s0[r] + s1[r] + s2[r] + s3[r];
    }
    // pack ef pieces
    unsigned pe2_0 = cvtpk(acc2[0], acc2[1]);
    unsigned pe2_1 = cvtpk(acc2[2], acc2[3]);
    unsigned psh_0 = cvtpk(shq[0], shq[1]);
    unsigned psh_1 = cvtpk(shq[2], shq[3]);
    // B-frag for GEMM2^T: lane needs ef[mloc][kblk*8..+8]
    fragu Bef;
    {
      const int s1l = mloc + 32 * (kblk & 1);
      const int s2l = s1l + 16;
      unsigned a0 = __shfl(pe2_0, s1l, 64);
      unsigned a1 = __shfl(pe2_1, s1l, 64);
      unsigned a2 = __shfl(pe2_0, s2l, 64);
      unsigned a3 = __shfl(pe2_1, s2l, 64);
      unsigned b0 = __shfl(psh_0, s1l, 64);
      unsigned b1 = __shfl(psh_1, s1l, 64);
      unsigned b2 = __shfl(psh_0, s2l, 64);
      unsigned b3 = __shfl(psh_1, s2l, 64);
      const bool lo2 = (kblk < 2);
      Bef.u[0] = lo2 ? a0 : b0; Bef.u[1] = lo2 ? a1 : b1;
      Bef.u[2] = lo2 ? a2 : b2; Bef.u[3] = lo2 ? a3 : b3;
    }
    // GEMM2^T + bn2a + relu -> pha (64 chans across 4 ntiles, packed)
    unsigned pha[8];
#pragma unroll
    for (int nt = 0; nt < 4; ++nt) {
      bf16x8 wa = FR(WS_W2A, nt * 64 + lane);
      f32x4 z = {0.f, 0.f, 0.f, 0.f};
      f32x4 c = MFMA(wa, Bef.v, z);
      f32x4 sA = *(const f32x4*)&bn2a_s[nt * 16 + kblk * 4];
      f32x4 bA = *(const f32x4*)&bn2a_b[nt * 16 + kblk * 4];
      float h0 = fmaxf(fmaf(c[0], sA[0], bA[0]), 0.f);
      float h1 = fmaxf(fmaf(c[1], sA[1], bA[1]), 0.f);
      float h2 = fmaxf(fmaf(c[2], sA[2], bA[2]), 0.f);
      float h3 = fmaxf(fmaf(c[3], sA[3], bA[3]), 0.f);
      pha[nt * 2 + 0] = cvtpk(h0, h1);
      pha[nt * 2 + 1] = cvtpk(h2, h3);
    }
    // GEMM3^T: h2 chans (0..7 valid) of neighbor mloc
    {
      const int sAl = mloc + 32 * (kblk & 1);
      const int sBl = sAl + 16;
      const bool lo2 = (kblk < 2);
      fragu B0, B1;
      {
        unsigned a0 = __shfl(pha[0], sAl, 64), a1 = __shfl(pha[1], sAl, 64);
        unsigned a2 = __shfl(pha[0], sBl, 64), a3 = __shfl(pha[1], sBl, 64);
        unsigned b0 = __shfl(pha[2], sAl, 64), b1 = __shfl(pha[3], sAl, 64);
        unsigned b2 = __shfl(pha[2], sBl, 64), b3 = __shfl(pha[3], sBl, 64);
        B0.u[0] = lo2 ? a0 : b0; B0.u[1] = lo2 ? a1 : b1;
        B0.u[2] = lo2 ? a2 : b2; B0.u[3] = lo2 ? a3 : b3;
      }
      {
        unsigned a0 = __shfl(pha[4], sAl, 64), a1 = __shfl(pha[5], sAl, 64);
        unsigned a2 = __shfl(pha[4], sBl, 64), a3 = __shfl(pha[5], sBl, 64);
        unsigned b0 = __shfl(pha[6], sAl, 64), b1 = __shfl(pha[7], sAl, 64);
        unsigned b2 = __shfl(pha[6], sBl, 64), b3 = __shfl(pha[7], sBl, 64);
        B1.u[0] = lo2 ? a0 : b0; B1.u[1] = lo2 ? a1 : b1;
        B1.u[2] = lo2 ? a2 : b2; B1.u[3] = lo2 ? a3 : b3;
      }
      f32x4 acc3 = {0.f, 0.f, 0.f, 0.f};
      acc3 = MFMA(FR(WS_W2B, 0 * 64 + lane), B0.v, acc3);
      acc3 = MFMA(FR(WS_W2B, 1 * 64 + lane), B1.v, acc3);
      f32x4 s = *(const f32x4*)&bn2b_s[(kblk & 1) * 4];
      f32x4 b = *(const f32x4*)&bn2b_b[(kblk & 1) * 4];
      float v0 = fmaxf(fmaf(acc3[0], s[0], b[0]), 0.f);
      float v1 = fmaxf(fmaf(acc3[1], s[1], b[1]), 0.f);
      float v2 = fmaxf(fmaf(acc3[2], s[2], b[2]), 0.f);
      float v3 = fmaxf(fmaf(acc3[3], s[3], b[3]), 0.f);
      h2p[g][0] = cvtpk(v0, v1);
      h2p[g][1] = cvtpk(v2, v3);
    }
  }

  // ---- route h2 to own row (thread row = tile kblk, neighbor mloc)
  unsigned hp0 = 0, hp1 = 0, hp2 = 0, hp3 = 0;
#pragma unroll
  for (int g = 0; g < 4; ++g) {
    unsigned t0 = __shfl(h2p[g][0], mloc, 64);
    unsigned t1 = __shfl(h2p[g][1], mloc, 64);
    unsigned t2 = __shfl(h2p[g][0], mloc + 16, 64);
    unsigned t3 = __shfl(h2p[g][1], mloc + 16, 64);
    const bool mine = (kblk == g);
    hp0 = mine ? t0 : hp0; hp1 = mine ? t1 : hp1;
    hp2 = mine ? t2 : hp2; hp3 = mine ? t3 : hp3;
  }
  float h2r[8];
  h2r[0] = bflo(hp0); h2r[1] = bfhi(hp0); h2r[2] = bflo(hp1); h2r[3] = bfhi(hp1);
  h2r[4] = bflo(hp2); h2r[5] = bfhi(hp2); h2r[6] = bflo(hp3); h2r[7] = bfhi(hp3);

  // ---- W2c + softmax over 16 neighbors
  float h3[8];
#pragma unroll
  for (int b = 0; b < 8; ++b) h3[b] = b2c[b];
#pragma unroll
  for (int m = 0; m < 8; ++m) {
    float r = h2r[m];
#pragma unroll
    for (int b = 0; b < 8; ++b) h3[b] = fmaf(r, W2c[m * 8 + b], h3[b]);
  }
  float wv[8];
#pragma unroll
  for (int b = 0; b < 8; ++b) {
    float mx = h3[b];
    mx = fmaxf(mx, __shfl_xor(mx, 1, 16));
    mx = fmaxf(mx, __shfl_xor(mx, 2, 16));
    mx = fmaxf(mx, __shfl_xor(mx, 4, 16));
    mx = fmaxf(mx, __shfl_xor(mx, 8, 16));
    float ex = __expf(h3[b] - mx);
    float s = ex;
    s += __shfl_xor(s, 1, 16);
    s += __shfl_xor(s, 2, 16);
    s += __shfl_xor(s, 4, 16);
    s += __shfl_xor(s, 8, 16);
    wv[b] = ex / s;
  }

  // ---- phase 2: x_knn = (y[idx] + pe) * w ; x_out = sum_j x_knn
  const float4* y4 = (const float4*)y;
  float* xkrow = x_knn + (long long)row * 64;
  float xo[4] = {0.f, 0.f, 0.f, 0.f};
#pragma unroll
  for (int h = 0; h < 2; ++h) {
    float4 yv[8];
#pragma unroll
    for (int u = 0; u < 8; ++u) yv[u] = y4[idx * 16 + h * 8 + u];
    f32x4 vout[8];
#pragma unroll
    for (int u = 0; u < 8; ++u) {
      float comp[4] = {yv[u].x, yv[u].y, yv[u].z, yv[u].w};
#pragma unroll
      for (int cc = 0; cc < 4; ++cc) {
        const int c = h * 32 + u * 4 + cc;
        float pe = bp2[c] + q0 * Wp2[c] + q1 * Wp2[64 + c] + q2 * Wp2[128 + c];
        float val = (comp[cc] + pe) * wv[c & 7];
        vout[u][cc] = val;
        float r = val;
        r += __shfl_xor(r, 1, 16);
        r += __shfl_xor(r, 2, 16);
        r += __shfl_xor(r, 4, 16);
        r += __shfl_xor(r, 8, 16);
        if (j == (c & 15)) xo[c >> 4] = r;
      }
    }
#pragma unroll
    for (int u = 0; u < 8; ++u)
      *(f32x4*)(xkrow + h * 32 + u * 4) = vout[u];
  }
#pragma unroll
  for (int g = 0; g < 4; ++g)
    x_out[n * 64 + g * 16 + j] = xo[g];

  // ---- optional fused tail (y lives in d_ws; no alias race)
  if (knn_f) {
    knn_f[row] = (float)idx;
    p_r[row * 3 + 0] = pr0;
    p_r[row * 3 + 1] = pr1;
    p_r[row * 3 + 2] = pr2;
  }
}

// ---------------------------------------------------------------------------
__global__ __launch_bounds__(256) void k_tail(
    const float* __restrict__ p, const int* __restrict__ knn,
    float* __restrict__ knn_f, float* __restrict__ p_r)
{
  int row = blockIdx.x * 256 + threadIdx.x;
  if (row >= NK) return;
  int n = row >> 4;
  int idx = knn[row];
  knn_f[row] = (float)idx;
  p_r[row * 3 + 0] = p[idx * 3 + 0] - p[n * 3 + 0];
  p_r[row * 3 + 1] = p[idx * 3 + 1] - p[n * 3 + 1];
  p_r[row * 3 + 2] = p[idx * 3 + 2] - p[n * 3 + 2];
}

// ---------------------------------------------------------------------------
extern "C" void kernel_launch(void* const* d_in, const int* in_sizes, int n_in,
                              void* d_out, int out_size, void* d_ws, size_t ws_size,
                              hipStream_t stream)
{
  const float* p    = (const float*)d_in[0];
  const float* x    = (const float*)d_in[1];
  const int*   knn  = (const int*)d_in[2];
  const float* W01  = (const float*)d_in[3];
  const float* b01  = (const float*)d_in[4];
  const float* Wbil = (const float*)d_in[5];
  const float* bbil = (const float*)d_in[6];
  const float* Wp1  = (const float*)d_in[7];
  const float* bp1  = (const float*)d_in[8];
  const float* bnps = (const float*)d_in[9];
  const float* bnpb = (const float*)d_in[10];
  const float* Wp2  = (const float*)d_in[11];
  const float* bp2  = (const float*)d_in[12];
  const float* W2a  = (const float*)d_in[13];
  const float* s2a  = (const float*)d_in[14];
  const float* b2a  = (const float*)d_in[15];
  const float* W2b  = (const float*)d_in[16];
  const float* s2b  = (const float*)d_in[17];
  const float* b2b  = (const float*)d_in[18];
  const float* W2c  = (const float*)d_in[19];
  const float* b2c  = (const float*)d_in[20];
  const float* W3   = (const float*)d_in[21];
  const float* b3   = (const float*)d_in[22];

  float* outF  = (float*)d_out;
  float* x_out = outF;                 // [N,64]
  float* x_knn = outF + 6400000;       // [N,16,64]
  float* knn_f = outF + 108800000;     // [N,16]
  float* p_r   = outF + 110400000;     // [N,16,3]
  short* wsf   = (short*)d_ws;

  const size_t yBytes = (size_t)NPTS * 64 * sizeof(float);
  const bool bigWs = ws_size >= (size_t)WS_BYTES + yBytes;
  float* y = bigWs ? (float*)((char*)d_ws + WS_BYTES) : knn_f;

  k_prep<<<1, 256, 0, stream>>>(W01, b01, Wbil, W2a, W2b, Wp2, bp2, wsf);
  k_xw3<<<25000, 256, 0, stream>>>(x, W3, b3, y);
  k_main<<<6250, 256, 0, stream>>>(p, x, knn, wsf, Wp1, bp1, bnps, bnpb,
                                   bbil, s2a, b2a, s2b, b2b, W2c, b2c,
                                   Wp2, bp2, y, x_out, x_knn,
                                   bigWs ? knn_f : (float*)nullptr,
                                   bigWs ? p_r : (float*)nullptr);
  if (!bigWs)
    k_tail<<<6250, 256, 0, stream>>>(p, knn, knn_f, p_r);
}

// Round 6
// 402.312 us; speedup vs baseline: 3.0782x; 1.0370x over previous
//
#include <hip/hip_runtime.h>

#define NPTS 100000
#define NK   1600000   // NPTS * 16

typedef __attribute__((ext_vector_type(8))) short bf16x8;
typedef __attribute__((ext_vector_type(4))) float f32x4;
typedef union { bf16x8 v; unsigned u[4]; } fragu;

#define MFMA(a,b,c) __builtin_amdgcn_mfma_f32_16x16x32_bf16((a),(b),(c),0,0,0)

// ws fragment-table offsets (in shorts). Layout per region: [(chunk*64+lane)*8+t]
// A-frag of W^T == B-frag of W under the shared k-enumeration.
#define WS_W01  0        // 3 chunks (K=96: k0..63=x@W01[3:], k64..66=pr, k67=b01)
#define WS_WBIL 1536     // 8 chunks (K=256: k=i*16+j -> Wbil[o][i][j])
#define WS_W2A  5632     // 4 ntiles (K=32)
#define WS_W2B  7680     // 2 chunks (K=64, cols 8..15 zero)
#define WS_WPE  8704     // 4 ntiles (K=32: k0..2=Wp2, k3=bp2, rest 0)
#define WS_BYTES 21504

__device__ inline unsigned cvtpk(float lo, float hi) {
  unsigned r;
  asm("v_cvt_pk_bf16_f32 %0, %1, %2" : "=v"(r) : "v"(lo), "v"(hi));
  return r;
}
__device__ inline short bfr(float f) {  // RNE f32->bf16 (finite inputs)
  unsigned u = __float_as_uint(f);
  u += 0x7fff + ((u >> 16) & 1);
  return (short)(u >> 16);
}
__device__ inline float bflo(unsigned u) { return __uint_as_float(u << 16); }
__device__ inline float bfhi(unsigned u) { return __uint_as_float(u & 0xffff0000u); }

// ---- cross-lane primitives -------------------------------------------------
// DPP (VALU pipe, zero LDS traffic). ctrl: quad_perm xor1=0xB1, xor2=0x4E,
// row_ror:N = 0x120+N (row = 16 lanes = one neighbor group).
template<int CTRL>
__device__ inline float fdpp(float x) {
  return __int_as_float(__builtin_amdgcn_update_dpp(
      0, __float_as_int(x), CTRL, 0xF, 0xF, true));
}
// ds_swizzle xor within 32 lanes (conflict-free permutation on LDS pipe)
template<int XM>
__device__ inline float fswz(float x) {
  return __int_as_float(__builtin_amdgcn_ds_swizzle(
      __float_as_int(x), 0x1F | (XM << 10)));
}
// arbitrary-source gather (LDS pipe)
__device__ inline unsigned bpermu(int src, unsigned v) {
  return (unsigned)__builtin_amdgcn_ds_bpermute(src << 2, (int)v);
}
__device__ inline float bpermf(int src, float v) {
  return __int_as_float(__builtin_amdgcn_ds_bpermute(src << 2, __float_as_int(v)));
}
__device__ inline int bpermi(int src, int v) {
  return __builtin_amdgcn_ds_bpermute(src << 2, v);
}

// ---------------------------------------------------------------------------
__global__ __launch_bounds__(256) void k_prep(
    const float* __restrict__ W01, const float* __restrict__ b01,
    const float* __restrict__ Wbil,
    const float* __restrict__ W2a, const float* __restrict__ W2b,
    const float* __restrict__ Wp2, const float* __restrict__ bp2,
    short* __restrict__ ws)
{
  const int t = threadIdx.x;
  for (int i = t; i < 3 * 512; i += 256) {
    int tt = i & 7, l = (i >> 3) & 63, kc = i >> 9;
    int o = l & 15, k = kc * 32 + ((l >> 4) << 3) + tt;
    float v = 0.f;
    if (k < 64) v = W01[(3 + k) * 16 + o];
    else if (k < 67) v = W01[(k - 64) * 16 + o];
    else if (k == 67) v = b01[o];
    ws[WS_W01 + i] = bfr(v);
  }
  for (int i = t; i < 8 * 512; i += 256) {
    int tt = i & 7, l = (i >> 3) & 63, kc = i >> 9;
    int o = l & 15, k = kc * 32 + ((l >> 4) << 3) + tt;
    ws[WS_WBIL + i] = bfr(Wbil[o * 256 + k]);
  }
  for (int i = t; i < 4 * 512; i += 256) {
    int tt = i & 7, l = (i >> 3) & 63, nt = i >> 9;
    int c = nt * 16 + (l & 15), k = ((l >> 4) << 3) + tt;
    ws[WS_W2A + i] = bfr(W2a[k * 64 + c]);
  }
  for (int i = t; i < 2 * 512; i += 256) {
    int tt = i & 7, l = (i >> 3) & 63, kc = i >> 9;
    int m = l & 15, k = kc * 32 + ((l >> 4) << 3) + tt;
    ws[WS_W2B + i] = bfr(m < 8 ? W2b[k * 8 + m] : 0.f);
  }
  for (int i = t; i < 4 * 512; i += 256) {
    int tt = i & 7, l = (i >> 3) & 63, nt = i >> 9;
    int c = nt * 16 + (l & 15), k = ((l >> 4) << 3) + tt;
    float v = 0.f;
    if (k < 3) v = Wp2[k * 64 + c]; else if (k == 3) v = bp2[c];
    ws[WS_WPE + i] = bfr(v);
  }
}

// ---------------------------------------------------------------------------
__global__ __launch_bounds__(256) void k_xw3(
    const float* __restrict__ x, const float* __restrict__ W3,
    const float* __restrict__ b3, float* __restrict__ y)
{
  int t = blockIdx.x * 256 + threadIdx.x;
  int i = __builtin_amdgcn_readfirstlane(t >> 6);
  int c = t & 63;
  if (i >= NPTS) return;
  const float* xr = x + i * 64;
  float acc = b3[c];
#pragma unroll
  for (int k = 0; k < 64; ++k)
    acc = fmaf(xr[k], W3[k * 64 + c], acc);
  y[i * 64 + c] = acc;
}

// ---------------------------------------------------------------------------
// Main: register-resident transposed MFMA chain, zero __shared__.
// Cross-lane: bpermute only where the pattern is an arbitrary gather;
// DPP for the 16-lane softmax allreduce; DPP+swizzle reduce-scatter for x_out.
// ---------------------------------------------------------------------------
__global__ __launch_bounds__(256, 5) void k_main(
    const float* __restrict__ p, const float* __restrict__ x,
    const int* __restrict__ knn, const short* __restrict__ wsf,
    const float* __restrict__ Wp1, const float* __restrict__ bp1,
    const float* __restrict__ bnp_s, const float* __restrict__ bnp_b,
    const float* __restrict__ bbil,
    const float* __restrict__ bn2a_s, const float* __restrict__ bn2a_b,
    const float* __restrict__ bn2b_s, const float* __restrict__ bn2b_b,
    const float* __restrict__ W2c, const float* __restrict__ b2c,
    const float* __restrict__ Wp2, const float* __restrict__ bp2,
    const float* __restrict__ y,
    float* __restrict__ x_out, float* __restrict__ x_knn,
    float* __restrict__ knn_f, float* __restrict__ p_r)   // may be null
{
  const int tid  = threadIdx.x;
  const int lane = tid & 63;
  const int mloc = lane & 15;
  const int kblk = lane >> 4;
  const int row  = blockIdx.x * 256 + tid;   // grid exact
  const int n    = row >> 4;
  const int j    = row & 15;
  const int idx  = knn[row];

  const float pr0 = p[idx * 3 + 0] - p[n * 3 + 0];
  const float pr1 = p[idx * 3 + 1] - p[n * 3 + 1];
  const float pr2 = p[idx * 3 + 2] - p[n * 3 + 2];

  // q = relu(bn(p_r @ Wp1 + bp1))
  float q0, q1, q2;
  {
    float v0 = bp1[0] + pr0 * Wp1[0] + pr1 * Wp1[3] + pr2 * Wp1[6];
    float v1 = bp1[1] + pr0 * Wp1[1] + pr1 * Wp1[4] + pr2 * Wp1[7];
    float v2 = bp1[2] + pr0 * Wp1[2] + pr1 * Wp1[5] + pr2 * Wp1[8];
    q0 = fmaxf(fmaf(v0, bnp_s[0], bnp_b[0]), 0.f);
    q1 = fmaxf(fmaf(v1, bnp_s[1], bnp_b[1]), 0.f);
    q2 = fmaxf(fmaf(v2, bnp_s[2], bnp_b[2]), 0.f);
  }

#define FR(off, idx_) (((const bf16x8*)wsf)[(off) / 8 + (idx_)])

  // ---- GEMM1^T: lane holds e chans kblk*4..+4 (packed bf16) of neighbor mloc
  unsigned epk[4][2];
  {
    bf16x8 bw0 = FR(WS_W01, 0 * 64 + lane);
    bf16x8 bw1 = FR(WS_W01, 1 * 64 + lane);
    bf16x8 bw2 = FR(WS_W01, 2 * 64 + lane);
    const float4* x4 = (const float4*)x;
#pragma unroll
    for (int g = 0; g < 4; ++g) {
      const int src = g * 16 + mloc;
      int   ridx = bpermi(src, idx);
      float p0s  = bpermf(src, pr0);
      float p1s  = bpermf(src, pr1);
      float p2s  = bpermf(src, pr2);
      f32x4 acc = {0.f, 0.f, 0.f, 0.f};
      {
        float4 xa = x4[ridx * 16 + kblk * 2];
        float4 xb = x4[ridx * 16 + kblk * 2 + 1];
        fragu B;
        B.u[0] = cvtpk(xa.x, xa.y); B.u[1] = cvtpk(xa.z, xa.w);
        B.u[2] = cvtpk(xb.x, xb.y); B.u[3] = cvtpk(xb.z, xb.w);
        acc = MFMA(bw0, B.v, acc);
      }
      {
        float4 xa = x4[ridx * 16 + 8 + kblk * 2];
        float4 xb = x4[ridx * 16 + 9 + kblk * 2];
        fragu B;
        B.u[0] = cvtpk(xa.x, xa.y); B.u[1] = cvtpk(xa.z, xa.w);
        B.u[2] = cvtpk(xb.x, xb.y); B.u[3] = cvtpk(xb.z, xb.w);
        acc = MFMA(bw1, B.v, acc);
      }
      {
        fragu B;
        B.u[0] = (kblk == 0) ? cvtpk(p0s, p1s) : 0u;
        B.u[1] = (kblk == 0) ? cvtpk(p2s, 1.f) : 0u;
        B.u[2] = 0u; B.u[3] = 0u;
        acc = MFMA(bw2, B.v, acc);
      }
      epk[g][0] = cvtpk(fmaxf(acc[0], 0.f), fmaxf(acc[1], 0.f));
      epk[g][1] = cvtpk(fmaxf(acc[2], 0.f), fmaxf(acc[3], 0.f));
    }
  }

  // ---- per-tile mid chain: bilinear^T, pe^T, GEMM2^T, GEMM3^T
  unsigned h2p[4][2];
#pragma unroll
  for (int g = 0; g < 4; ++g) {
    float er[16];
    {
      unsigned a0 = bpermu(mloc,      epk[g][0]);
      unsigned a1 = bpermu(mloc,      epk[g][1]);
      unsigned b0 = bpermu(mloc + 16, epk[g][0]);
      unsigned b1 = bpermu(mloc + 16, epk[g][1]);
      unsigned c0 = bpermu(mloc + 32, epk[g][0]);
      unsigned c1 = bpermu(mloc + 32, epk[g][1]);
      unsigned d0 = bpermu(mloc + 48, epk[g][0]);
      unsigned d1 = bpermu(mloc + 48, epk[g][1]);
      er[0] = bflo(a0);  er[1] = bfhi(a0);  er[2]  = bflo(a1); er[3]  = bfhi(a1);
      er[4] = bflo(b0);  er[5] = bfhi(b0);  er[6]  = bflo(b1); er[7]  = bfhi(b1);
      er[8] = bflo(c0);  er[9] = bfhi(c0);  er[10] = bflo(c1); er[11] = bfhi(c1);
      er[12] = bflo(d0); er[13] = bfhi(d0); er[14] = bflo(d1); er[15] = bfhi(d1);
    }
    const int jhsel = kblk & 1, ihsel = kblk >> 1;
    float ej[8];
#pragma unroll
    for (int t = 0; t < 8; ++t) ej[t] = jhsel ? er[8 + t] : er[t];
    f32x4 acc2;
    {
      f32x4 bb = *(const f32x4*)&bbil[kblk * 4];
      acc2 = bb;
#pragma unroll
      for (int kc = 0; kc < 8; ++kc) {
        bf16x8 wb = FR(WS_WBIL, kc * 64 + lane);
        float ei = ihsel ? er[2 * kc + 1] : er[2 * kc];
        fragu B;
        B.u[0] = cvtpk(ei * ej[0], ei * ej[1]);
        B.u[1] = cvtpk(ei * ej[2], ei * ej[3]);
        B.u[2] = cvtpk(ei * ej[4], ei * ej[5]);
        B.u[3] = cvtpk(ei * ej[6], ei * ej[7]);
        acc2 = MFMA(wb, B.v, acc2);
      }
    }
    // pe^T -> shrink
    f32x4 shq;
    {
      const int src = g * 16 + mloc;
      float q0s = bpermf(src, q0);
      float q1s = bpermf(src, q1);
      float q2s = bpermf(src, q2);
      fragu B;
      B.u[0] = (kblk == 0) ? cvtpk(q0s, q1s) : 0u;
      B.u[1] = (kblk == 0) ? cvtpk(q2s, 1.f) : 0u;
      B.u[2] = 0u; B.u[3] = 0u;
      f32x4 z = {0.f, 0.f, 0.f, 0.f};
      f32x4 s0 = MFMA(FR(WS_WPE, 0 * 64 + lane), B.v, z);
      f32x4 s1 = MFMA(FR(WS_WPE, 1 * 64 + lane), B.v, z);
      f32x4 s2 = MFMA(FR(WS_WPE, 2 * 64 + lane), B.v, z);
      f32x4 s3 = MFMA(FR(WS_WPE, 3 * 64 + lane), B.v, z);
#pragma unroll
      for (int r = 0; r < 4; ++r) shq[r] = s0[r] + s1[r] + s2[r] + s3[r];
    }
    unsigned pe2_0 = cvtpk(acc2[0], acc2[1]);
    unsigned pe2_1 = cvtpk(acc2[2], acc2[3]);
    unsigned psh_0 = cvtpk(shq[0], shq[1]);
    unsigned psh_1 = cvtpk(shq[2], shq[3]);
    fragu Bef;
    {
      const int s1l = mloc + 32 * (kblk & 1);
      const int s2l = s1l + 16;
      unsigned a0 = bpermu(s1l, pe2_0);
      unsigned a1 = bpermu(s1l, pe2_1);
      unsigned a2 = bpermu(s2l, pe2_0);
      unsigned a3 = bpermu(s2l, pe2_1);
      unsigned b0 = bpermu(s1l, psh_0);
      unsigned b1 = bpermu(s1l, psh_1);
      unsigned b2 = bpermu(s2l, psh_0);
      unsigned b3 = bpermu(s2l, psh_1);
      const bool lo2 = (kblk < 2);
      Bef.u[0] = lo2 ? a0 : b0; Bef.u[1] = lo2 ? a1 : b1;
      Bef.u[2] = lo2 ? a2 : b2; Bef.u[3] = lo2 ? a3 : b3;
    }
    unsigned pha[8];
#pragma unroll
    for (int nt = 0; nt < 4; ++nt) {
      bf16x8 wa = FR(WS_W2A, nt * 64 + lane);
      f32x4 z = {0.f, 0.f, 0.f, 0.f};
      f32x4 c = MFMA(wa, Bef.v, z);
      f32x4 sA = *(const f32x4*)&bn2a_s[nt * 16 + kblk * 4];
      f32x4 bA = *(const f32x4*)&bn2a_b[nt * 16 + kblk * 4];
      float h0 = fmaxf(fmaf(c[0], sA[0], bA[0]), 0.f);
      float h1 = fmaxf(fmaf(c[1], sA[1], bA[1]), 0.f);
      float h2 = fmaxf(fmaf(c[2], sA[2], bA[2]), 0.f);
      float h3 = fmaxf(fmaf(c[3], sA[3], bA[3]), 0.f);
      pha[nt * 2 + 0] = cvtpk(h0, h1);
      pha[nt * 2 + 1] = cvtpk(h2, h3);
    }
    {
      const int sAl = mloc + 32 * (kblk & 1);
      const int sBl = sAl + 16;
      const bool lo2 = (kblk < 2);
      fragu B0, B1;
      {
        unsigned a0 = bpermu(sAl, pha[0]), a1 = bpermu(sAl, pha[1]);
        unsigned a2 = bpermu(sBl, pha[0]), a3 = bpermu(sBl, pha[1]);
        unsigned b0 = bpermu(sAl, pha[2]), b1 = bpermu(sAl, pha[3]);
        unsigned b2 = bpermu(sBl, pha[2]), b3 = bpermu(sBl, pha[3]);
        B0.u[0] = lo2 ? a0 : b0; B0.u[1] = lo2 ? a1 : b1;
        B0.u[2] = lo2 ? a2 : b2; B0.u[3] = lo2 ? a3 : b3;
      }
      {
        unsigned a0 = bpermu(sAl, pha[4]), a1 = bpermu(sAl, pha[5]);
        unsigned a2 = bpermu(sBl, pha[4]), a3 = bpermu(sBl, pha[5]);
        unsigned b0 = bpermu(sAl, pha[6]), b1 = bpermu(sAl, pha[7]);
        unsigned b2 = bpermu(sBl, pha[6]), b3 = bpermu(sBl, pha[7]);
        B1.u[0] = lo2 ? a0 : b0; B1.u[1] = lo2 ? a1 : b1;
        B1.u[2] = lo2 ? a2 : b2; B1.u[3] = lo2 ? a3 : b3;
      }
      f32x4 acc3 = {0.f, 0.f, 0.f, 0.f};
      acc3 = MFMA(FR(WS_W2B, 0 * 64 + lane), B0.v, acc3);
      acc3 = MFMA(FR(WS_W2B, 1 * 64 + lane), B1.v, acc3);
      f32x4 s = *(const f32x4*)&bn2b_s[(kblk & 1) * 4];
      f32x4 b = *(const f32x4*)&bn2b_b[(kblk & 1) * 4];
      float v0 = fmaxf(fmaf(acc3[0], s[0], b[0]), 0.f);
      float v1 = fmaxf(fmaf(acc3[1], s[1], b[1]), 0.f);
      float v2 = fmaxf(fmaf(acc3[2], s[2], b[2]), 0.f);
      float v3 = fmaxf(fmaf(acc3[3], s[3], b[3]), 0.f);
      h2p[g][0] = cvtpk(v0, v1);
      h2p[g][1] = cvtpk(v2, v3);
    }
  }

  // ---- route h2 to own row (tile kblk, neighbor mloc)
  unsigned hp0 = 0, hp1 = 0, hp2 = 0, hp3 = 0;
#pragma unroll
  for (int g = 0; g < 4; ++g) {
    unsigned t0 = bpermu(mloc,      h2p[g][0]);
    unsigned t1 = bpermu(mloc,      h2p[g][1]);
    unsigned t2 = bpermu(mloc + 16, h2p[g][0]);
    unsigned t3 = bpermu(mloc + 16, h2p[g][1]);
    const bool mine = (kblk == g);
    hp0 = mine ? t0 : hp0; hp1 = mine ? t1 : hp1;
    hp2 = mine ? t2 : hp2; hp3 = mine ? t3 : hp3;
  }
  float h2r[8];
  h2r[0] = bflo(hp0); h2r[1] = bfhi(hp0); h2r[2] = bflo(hp1); h2r[3] = bfhi(hp1);
  h2r[4] = bflo(hp2); h2r[5] = bfhi(hp2); h2r[6] = bflo(hp3); h2r[7] = bfhi(hp3);

  // ---- W2c + softmax over 16 neighbors (DPP ror allreduce: zero LDS ops)
  float h3[8];
#pragma unroll
  for (int b = 0; b < 8; ++b) h3[b] = b2c[b];
#pragma unroll
  for (int m = 0; m < 8; ++m) {
    float r = h2r[m];
#pragma unroll
    for (int b = 0; b < 8; ++b) h3[b] = fmaf(r, W2c[m * 8 + b], h3[b]);
  }
  float wv[8];
#pragma unroll
  for (int b = 0; b < 8; ++b) {
    float mx = h3[b];
    mx = fmaxf(mx, fdpp<0x128>(mx));
    mx = fmaxf(mx, fdpp<0x124>(mx));
    mx = fmaxf(mx, fdpp<0x122>(mx));
    mx = fmaxf(mx, fdpp<0x121>(mx));
    float ex = __expf(h3[b] - mx);
    float s = ex;
    s = s + fdpp<0x128>(s);
    s = s + fdpp<0x124>(s);
    s = s + fdpp<0x122>(s);
    s = s + fdpp<0x121>(s);
    wv[b] = ex * __builtin_amdgcn_rcpf(s);
  }

  // ---- phase 2: x_knn = (y[idx] + pe) * w ; x_out via hybrid reduce-scatter
  const float4* y4 = (const float4*)y;
  float* xkrow = x_knn + (long long)row * 64;
  float xo[4];
#pragma unroll
  for (int h = 0; h < 2; ++h) {
    float4 yv[8];
#pragma unroll
    for (int u = 0; u < 8; ++u) yv[u] = y4[idx * 16 + h * 8 + u];
    float v[32];
#pragma unroll
    for (int u = 0; u < 8; ++u) {
      float comp[4] = {yv[u].x, yv[u].y, yv[u].z, yv[u].w};
      f32x4 st;
#pragma unroll
      for (int cc = 0; cc < 4; ++cc) {
        const int c = h * 32 + u * 4 + cc;
        float pe = bp2[c] + q0 * Wp2[c] + q1 * Wp2[64 + c] + q2 * Wp2[128 + c];
        float val = (comp[cc] + pe) * wv[c & 7];
        v[u * 4 + cc] = val;
        st[cc] = val;
      }
      *(f32x4*)(xkrow + h * 32 + u * 4) = st;
    }
    // reduce-scatter over the 16-lane group: bits 0,1 via DPP quad_perm,
    // bits 2,3 via ds_swizzle xor. Lane j ends with channels h*32+j, h*32+16+j.
    const bool b0 = (j & 1), b1 = (j & 2), b2 = (j & 4), b3 = (j & 8);
    float v1[16];
#pragma unroll
    for (int q = 0; q < 16; ++q) {
      float snd = b0 ? v[2 * q] : v[2 * q + 1];
      float rcv = fdpp<0xB1>(snd);
      v1[q] = (b0 ? v[2 * q + 1] : v[2 * q]) + rcv;
    }
    float v2[8];
#pragma unroll
    for (int r = 0; r < 8; ++r) {
      float snd = b1 ? v1[2 * r] : v1[2 * r + 1];
      float rcv = fdpp<0x4E>(snd);
      v2[r] = (b1 ? v1[2 * r + 1] : v1[2 * r]) + rcv;
    }
    float v3[4];
#pragma unroll
    for (int s = 0; s < 4; ++s) {
      float snd = b2 ? v2[2 * s] : v2[2 * s + 1];
      float rcv = fswz<4>(snd);
      v3[s] = (b2 ? v2[2 * s + 1] : v2[2 * s]) + rcv;
    }
    {
      float s0 = b3 ? v3[0] : v3[1];
      float s1 = b3 ? v3[2] : v3[3];
      float r0 = fswz<8>(s0);
      float r1 = fswz<8>(s1);
      xo[2 * h]     = (b3 ? v3[1] : v3[0]) + r0;
      xo[2 * h + 1] = (b3 ? v3[3] : v3[2]) + r1;
    }
  }
#pragma unroll
  for (int g = 0; g < 4; ++g)
    x_out[n * 64 + g * 16 + j] = xo[g];

  // ---- optional fused tail (y lives in d_ws; no alias race)
  if (knn_f) {
    knn_f[row] = (float)idx;
    p_r[row * 3 + 0] = pr0;
    p_r[row * 3 + 1] = pr1;
    p_r[row * 3 + 2] = pr2;
  }
}

// ---------------------------------------------------------------------------
__global__ __launch_bounds__(256) void k_tail(
    const float* __restrict__ p, const int* __restrict__ knn,
    float* __restrict__ knn_f, float* __restrict__ p_r)
{
  int row = blockIdx.x * 256 + threadIdx.x;
  if (row >= NK) return;
  int n = row >> 4;
  int idx = knn[row];
  knn_f[row] = (float)idx;
  p_r[row * 3 + 0] = p[idx * 3 + 0] - p[n * 3 + 0];
  p_r[row * 3 + 1] = p[idx * 3 + 1] - p[n * 3 + 1];
  p_r[row * 3 + 2] = p[idx * 3 + 2] - p[n * 3 + 2];
}

// ---------------------------------------------------------------------------
extern "C" void kernel_launch(void* const* d_in, const int* in_sizes, int n_in,
                              void* d_out, int out_size, void* d_ws, size_t ws_size,
                              hipStream_t stream)
{
  const float* p    = (const float*)d_in[0];
  const float* x    = (const float*)d_in[1];
  const int*   knn  = (const int*)d_in[2];
  const float* W01  = (const float*)d_in[3];
  const float* b01  = (const float*)d_in[4];
  const float* Wbil = (const float*)d_in[5];
  const float* bbil = (const float*)d_in[6];
  const float* Wp1  = (const float*)d_in[7];
  const float* bp1  = (const float*)d_in[8];
  const float* bnps = (const float*)d_in[9];
  const float* bnpb = (const float*)d_in[10];
  const float* Wp2  = (const float*)d_in[11];
  const float* bp2  = (const float*)d_in[12];
  const float* W2a  = (const float*)d_in[13];
  const float* s2a  = (const float*)d_in[14];
  const float* b2a  = (const float*)d_in[15];
  const float* W2b  = (const float*)d_in[16];
  const float* s2b  = (const float*)d_in[17];
  const float* b2b  = (const float*)d_in[18];
  const float* W2c  = (const float*)d_in[19];
  const float* b2c  = (const float*)d_in[20];
  const float* W3   = (const float*)d_in[21];
  const float* b3   = (const float*)d_in[22];

  float* outF  = (float*)d_out;
  float* x_out = outF;                 // [N,64]
  float* x_knn = outF + 6400000;       // [N,16,64]
  float* knn_f = outF + 108800000;     // [N,16]
  float* p_r   = outF + 110400000;     // [N,16,3]
  short* wsf   = (short*)d_ws;

  const size_t yBytes = (size_t)NPTS * 64 * sizeof(float);
  const bool bigWs = ws_size >= (size_t)WS_BYTES + yBytes;
  float* y = bigWs ? (float*)((char*)d_ws + WS_BYTES) : knn_f;

  k_prep<<<1, 256, 0, stream>>>(W01, b01, Wbil, W2a, W2b, Wp2, bp2, wsf);
  k_xw3<<<25000, 256, 0, stream>>>(x, W3, b3, y);
  k_main<<<6250, 256, 0, stream>>>(p, x, knn, wsf, Wp1, bp1, bnps, bnpb,
                                   bbil, s2a, b2a, s2b, b2b, W2c, b2c,
                                   Wp2, bp2, y, x_out, x_knn,
                                   bigWs ? knn_f : (float*)nullptr,
                                   bigWs ? p_r : (float*)nullptr);
  if (!bigWs)
    k_tail<<<6250, 256, 0, stream>>>(p, knn, knn_f, p_r);
}

// Round 7
// 369.695 us; speedup vs baseline: 3.3498x; 1.0882x over previous
//
#include <hip/hip_runtime.h>

#define NPTS 100000
#define NK   1600000   // NPTS * 16

typedef __attribute__((ext_vector_type(8))) short bf16x8;
typedef __attribute__((ext_vector_type(4))) float f32x4;
typedef union { bf16x8 v; unsigned u[4]; } fragu;

#define MFMA(a,b,c) __builtin_amdgcn_mfma_f32_16x16x32_bf16((a),(b),(c),0,0,0)

// ws layout: fragment tables, then bf16 copies of x and y.
#define WS_W01  0
#define WS_WBIL 1536
#define WS_W2A  5632
#define WS_W2B  7680
#define WS_WPE  8704
#define WS_BYTES 21504                         // tables (shorts*2)
#define WS_XBF   WS_BYTES                      // 100000*64*2 = 12,800,000 B
#define WS_YBF   (WS_BYTES + 12800000)         // 12,800,000 B
#define WS_NEED  (WS_BYTES + 25600000)

__device__ inline unsigned cvtpk(float lo, float hi) {
  unsigned r;
  asm("v_cvt_pk_bf16_f32 %0, %1, %2" : "=v"(r) : "v"(lo), "v"(hi));
  return r;
}
__device__ inline short bfr(float f) {  // RNE f32->bf16
  unsigned u = __float_as_uint(f);
  u += 0x7fff + ((u >> 16) & 1);
  return (short)(u >> 16);
}
__device__ inline float bflo(unsigned u) { return __uint_as_float(u << 16); }
__device__ inline float bfhi(unsigned u) { return __uint_as_float(u & 0xffff0000u); }

template<int CTRL>
__device__ inline float fdpp(float x) {
  return __int_as_float(__builtin_amdgcn_update_dpp(
      0, __float_as_int(x), CTRL, 0xF, 0xF, true));
}
template<int XM>
__device__ inline float fswz(float x) {
  return __int_as_float(__builtin_amdgcn_ds_swizzle(
      __float_as_int(x), 0x1F | (XM << 10)));
}
__device__ inline unsigned bpermu(int src, unsigned v) {
  return (unsigned)__builtin_amdgcn_ds_bpermute(src << 2, (int)v);
}
__device__ inline float bpermf(int src, float v) {
  return __int_as_float(__builtin_amdgcn_ds_bpermute(src << 2, __float_as_int(v)));
}
__device__ inline int bpermi(int src, int v) {
  return __builtin_amdgcn_ds_bpermute(src << 2, v);
}

// ---------------------------------------------------------------------------
__global__ __launch_bounds__(256) void k_prep(
    const float* __restrict__ W01, const float* __restrict__ b01,
    const float* __restrict__ Wbil,
    const float* __restrict__ W2a, const float* __restrict__ W2b,
    const float* __restrict__ Wp2, const float* __restrict__ bp2,
    short* __restrict__ ws)
{
  const int t = threadIdx.x;
  for (int i = t; i < 3 * 512; i += 256) {
    int tt = i & 7, l = (i >> 3) & 63, kc = i >> 9;
    int o = l & 15, k = kc * 32 + ((l >> 4) << 3) + tt;
    float v = 0.f;
    if (k < 64) v = W01[(3 + k) * 16 + o];
    else if (k < 67) v = W01[(k - 64) * 16 + o];
    else if (k == 67) v = b01[o];
    ws[WS_W01 + i] = bfr(v);
  }
  for (int i = t; i < 8 * 512; i += 256) {
    int tt = i & 7, l = (i >> 3) & 63, kc = i >> 9;
    int o = l & 15, k = kc * 32 + ((l >> 4) << 3) + tt;
    ws[WS_WBIL + i] = bfr(Wbil[o * 256 + k]);
  }
  for (int i = t; i < 4 * 512; i += 256) {
    int tt = i & 7, l = (i >> 3) & 63, nt = i >> 9;
    int c = nt * 16 + (l & 15), k = ((l >> 4) << 3) + tt;
    ws[WS_W2A + i] = bfr(W2a[k * 64 + c]);
  }
  for (int i = t; i < 2 * 512; i += 256) {
    int tt = i & 7, l = (i >> 3) & 63, kc = i >> 9;
    int m = l & 15, k = kc * 32 + ((l >> 4) << 3) + tt;
    ws[WS_W2B + i] = bfr(m < 8 ? W2b[k * 8 + m] : 0.f);
  }
  for (int i = t; i < 4 * 512; i += 256) {
    int tt = i & 7, l = (i >> 3) & 63, nt = i >> 9;
    int c = nt * 16 + (l & 15), k = ((l >> 4) << 3) + tt;
    float v = 0.f;
    if (k < 3) v = Wp2[k * 64 + c]; else if (k == 3) v = bp2[c];
    ws[WS_WPE + i] = bfr(v);
  }
}

// ---------------------------------------------------------------------------
// x (f32) -> x_bf (bf16), elementwise. 6.4M elems, 4 per thread.
__global__ __launch_bounds__(256) void k_cvt(
    const float* __restrict__ x, unsigned* __restrict__ xb2)
{
  int t = blockIdx.x * 256 + threadIdx.x;   // 6250*256*4 = 6.4M exact
  f32x4 v = *(const f32x4*)&x[t * 4];
  uint2 o; o.x = cvtpk(v[0], v[1]); o.y = cvtpk(v[2], v[3]);
  *(uint2*)&xb2[t * 2] = o;
}

// ---------------------------------------------------------------------------
template<bool BF>
__global__ __launch_bounds__(256) void k_xw3(
    const float* __restrict__ x, const float* __restrict__ W3,
    const float* __restrict__ b3, void* __restrict__ yout)
{
  int t = blockIdx.x * 256 + threadIdx.x;
  int i = __builtin_amdgcn_readfirstlane(t >> 6);
  int c = t & 63;
  if (i >= NPTS) return;
  const float* xr = x + i * 64;
  float acc = b3[c];
#pragma unroll
  for (int k = 0; k < 64; ++k)
    acc = fmaf(xr[k], W3[k * 64 + c], acc);
  if constexpr (BF) ((short*)yout)[i * 64 + c] = bfr(acc);
  else              ((float*)yout)[i * 64 + c] = acc;
}

// ---------------------------------------------------------------------------
// Main: register-resident transposed MFMA chain, zero __shared__.
// BF=true: x and y gathered as bf16 (half bytes, half requests).
// ---------------------------------------------------------------------------
template<bool BF>
__global__ __launch_bounds__(256, 5) void k_main(
    const float* __restrict__ p, const float* __restrict__ x,
    const int* __restrict__ knn, const short* __restrict__ wsf,
    const float* __restrict__ Wp1, const float* __restrict__ bp1,
    const float* __restrict__ bnp_s, const float* __restrict__ bnp_b,
    const float* __restrict__ bbil,
    const float* __restrict__ bn2a_s, const float* __restrict__ bn2a_b,
    const float* __restrict__ bn2b_s, const float* __restrict__ bn2b_b,
    const float* __restrict__ W2c, const float* __restrict__ b2c,
    const float* __restrict__ Wp2, const float* __restrict__ bp2,
    const void* __restrict__ yv_, const void* __restrict__ xbf_,
    float* __restrict__ x_out, float* __restrict__ x_knn,
    float* __restrict__ knn_f, float* __restrict__ p_r)   // may be null
{
  const int tid  = threadIdx.x;
  const int lane = tid & 63;
  const int mloc = lane & 15;
  const int kblk = lane >> 4;
  const int row  = blockIdx.x * 256 + tid;   // grid exact
  const int n    = row >> 4;
  const int j    = row & 15;
  const int idx  = knn[row];

  const float pr0 = p[idx * 3 + 0] - p[n * 3 + 0];
  const float pr1 = p[idx * 3 + 1] - p[n * 3 + 1];
  const float pr2 = p[idx * 3 + 2] - p[n * 3 + 2];

  float q0, q1, q2;
  {
    float v0 = bp1[0] + pr0 * Wp1[0] + pr1 * Wp1[3] + pr2 * Wp1[6];
    float v1 = bp1[1] + pr0 * Wp1[1] + pr1 * Wp1[4] + pr2 * Wp1[7];
    float v2 = bp1[2] + pr0 * Wp1[2] + pr1 * Wp1[5] + pr2 * Wp1[8];
    q0 = fmaxf(fmaf(v0, bnp_s[0], bnp_b[0]), 0.f);
    q1 = fmaxf(fmaf(v1, bnp_s[1], bnp_b[1]), 0.f);
    q2 = fmaxf(fmaf(v2, bnp_s[2], bnp_b[2]), 0.f);
  }

#define FR(off, idx_) (((const bf16x8*)wsf)[(off) / 8 + (idx_)])

  // ---- GEMM1^T: lane holds e chans kblk*4..+4 (packed bf16) of neighbor mloc
  unsigned epk[4][2];
  {
    bf16x8 bw0 = FR(WS_W01, 0 * 64 + lane);
    bf16x8 bw1 = FR(WS_W01, 1 * 64 + lane);
    bf16x8 bw2 = FR(WS_W01, 2 * 64 + lane);
    const float4* x4 = (const float4*)x;
    const bf16x8* xb8 = (const bf16x8*)xbf_;
#pragma unroll
    for (int g = 0; g < 4; ++g) {
      const int src = g * 16 + mloc;
      int   ridx = bpermi(src, idx);
      float p0s  = bpermf(src, pr0);
      float p1s  = bpermf(src, pr1);
      float p2s  = bpermf(src, pr2);
      f32x4 acc = {0.f, 0.f, 0.f, 0.f};
      if constexpr (BF) {
        bf16x8 B0 = xb8[ridx * 8 + kblk];
        bf16x8 B1 = xb8[ridx * 8 + 4 + kblk];
        acc = MFMA(bw0, B0, acc);
        acc = MFMA(bw1, B1, acc);
      } else {
        {
          float4 xa = x4[ridx * 16 + kblk * 2];
          float4 xb = x4[ridx * 16 + kblk * 2 + 1];
          fragu B;
          B.u[0] = cvtpk(xa.x, xa.y); B.u[1] = cvtpk(xa.z, xa.w);
          B.u[2] = cvtpk(xb.x, xb.y); B.u[3] = cvtpk(xb.z, xb.w);
          acc = MFMA(bw0, B.v, acc);
        }
        {
          float4 xa = x4[ridx * 16 + 8 + kblk * 2];
          float4 xb = x4[ridx * 16 + 9 + kblk * 2];
          fragu B;
          B.u[0] = cvtpk(xa.x, xa.y); B.u[1] = cvtpk(xa.z, xa.w);
          B.u[2] = cvtpk(xb.x, xb.y); B.u[3] = cvtpk(xb.z, xb.w);
          acc = MFMA(bw1, B.v, acc);
        }
      }
      {
        fragu B;
        B.u[0] = (kblk == 0) ? cvtpk(p0s, p1s) : 0u;
        B.u[1] = (kblk == 0) ? cvtpk(p2s, 1.f) : 0u;
        B.u[2] = 0u; B.u[3] = 0u;
        acc = MFMA(bw2, B.v, acc);
      }
      epk[g][0] = cvtpk(fmaxf(acc[0], 0.f), fmaxf(acc[1], 0.f));
      epk[g][1] = cvtpk(fmaxf(acc[2], 0.f), fmaxf(acc[3], 0.f));
    }
  }

  // ---- per-tile mid chain: bilinear^T, pe^T, GEMM2^T, GEMM3^T
  unsigned h2p[4][2];
#pragma unroll
  for (int g = 0; g < 4; ++g) {
    float er[16];
    {
      unsigned a0 = bpermu(mloc,      epk[g][0]);
      unsigned a1 = bpermu(mloc,      epk[g][1]);
      unsigned b0 = bpermu(mloc + 16, epk[g][0]);
      unsigned b1 = bpermu(mloc + 16, epk[g][1]);
      unsigned c0 = bpermu(mloc + 32, epk[g][0]);
      unsigned c1 = bpermu(mloc + 32, epk[g][1]);
      unsigned d0 = bpermu(mloc + 48, epk[g][0]);
      unsigned d1 = bpermu(mloc + 48, epk[g][1]);
      er[0] = bflo(a0);  er[1] = bfhi(a0);  er[2]  = bflo(a1); er[3]  = bfhi(a1);
      er[4] = bflo(b0);  er[5] = bfhi(b0);  er[6]  = bflo(b1); er[7]  = bfhi(b1);
      er[8] = bflo(c0);  er[9] = bfhi(c0);  er[10] = bflo(c1); er[11] = bfhi(c1);
      er[12] = bflo(d0); er[13] = bfhi(d0); er[14] = bflo(d1); er[15] = bfhi(d1);
    }
    const int jhsel = kblk & 1, ihsel = kblk >> 1;
    float ej[8];
#pragma unroll
    for (int t = 0; t < 8; ++t) ej[t] = jhsel ? er[8 + t] : er[t];
    f32x4 acc2;
    {
      f32x4 bb = *(const f32x4*)&bbil[kblk * 4];
      acc2 = bb;
#pragma unroll
      for (int kc = 0; kc < 8; ++kc) {
        bf16x8 wb = FR(WS_WBIL, kc * 64 + lane);
        float ei = ihsel ? er[2 * kc + 1] : er[2 * kc];
        fragu B;
        B.u[0] = cvtpk(ei * ej[0], ei * ej[1]);
        B.u[1] = cvtpk(ei * ej[2], ei * ej[3]);
        B.u[2] = cvtpk(ei * ej[4], ei * ej[5]);
        B.u[3] = cvtpk(ei * ej[6], ei * ej[7]);
        acc2 = MFMA(wb, B.v, acc2);
      }
    }
    f32x4 shq;
    {
      const int src = g * 16 + mloc;
      float q0s = bpermf(src, q0);
      float q1s = bpermf(src, q1);
      float q2s = bpermf(src, q2);
      fragu B;
      B.u[0] = (kblk == 0) ? cvtpk(q0s, q1s) : 0u;
      B.u[1] = (kblk == 0) ? cvtpk(q2s, 1.f) : 0u;
      B.u[2] = 0u; B.u[3] = 0u;
      f32x4 z = {0.f, 0.f, 0.f, 0.f};
      f32x4 s0 = MFMA(FR(WS_WPE, 0 * 64 + lane), B.v, z);
      f32x4 s1 = MFMA(FR(WS_WPE, 1 * 64 + lane), B.v, z);
      f32x4 s2 = MFMA(FR(WS_WPE, 2 * 64 + lane), B.v, z);
      f32x4 s3 = MFMA(FR(WS_WPE, 3 * 64 + lane), B.v, z);
#pragma unroll
      for (int r = 0; r < 4; ++r) shq[r] = s0[r] + s1[r] + s2[r] + s3[r];
    }
    unsigned pe2_0 = cvtpk(acc2[0], acc2[1]);
    unsigned pe2_1 = cvtpk(acc2[2], acc2[3]);
    unsigned psh_0 = cvtpk(shq[0], shq[1]);
    unsigned psh_1 = cvtpk(shq[2], shq[3]);
    fragu Bef;
    {
      const int s1l = mloc + 32 * (kblk & 1);
      const int s2l = s1l + 16;
      unsigned a0 = bpermu(s1l, pe2_0);
      unsigned a1 = bpermu(s1l, pe2_1);
      unsigned a2 = bpermu(s2l, pe2_0);
      unsigned a3 = bpermu(s2l, pe2_1);
      unsigned b0 = bpermu(s1l, psh_0);
      unsigned b1 = bpermu(s1l, psh_1);
      unsigned b2 = bpermu(s2l, psh_0);
      unsigned b3 = bpermu(s2l, psh_1);
      const bool lo2 = (kblk < 2);
      Bef.u[0] = lo2 ? a0 : b0; Bef.u[1] = lo2 ? a1 : b1;
      Bef.u[2] = lo2 ? a2 : b2; Bef.u[3] = lo2 ? a3 : b3;
    }
    unsigned pha[8];
#pragma unroll
    for (int nt = 0; nt < 4; ++nt) {
      bf16x8 wa = FR(WS_W2A, nt * 64 + lane);
      f32x4 z = {0.f, 0.f, 0.f, 0.f};
      f32x4 c = MFMA(wa, Bef.v, z);
      f32x4 sA = *(const f32x4*)&bn2a_s[nt * 16 + kblk * 4];
      f32x4 bA = *(const f32x4*)&bn2a_b[nt * 16 + kblk * 4];
      float h0 = fmaxf(fmaf(c[0], sA[0], bA[0]), 0.f);
      float h1 = fmaxf(fmaf(c[1], sA[1], bA[1]), 0.f);
      float h2 = fmaxf(fmaf(c[2], sA[2], bA[2]), 0.f);
      float h3 = fmaxf(fmaf(c[3], sA[3], bA[3]), 0.f);
      pha[nt * 2 + 0] = cvtpk(h0, h1);
      pha[nt * 2 + 1] = cvtpk(h2, h3);
    }
    {
      const int sAl = mloc + 32 * (kblk & 1);
      const int sBl = sAl + 16;
      const bool lo2 = (kblk < 2);
      fragu B0, B1;
      {
        unsigned a0 = bpermu(sAl, pha[0]), a1 = bpermu(sAl, pha[1]);
        unsigned a2 = bpermu(sBl, pha[0]), a3 = bpermu(sBl, pha[1]);
        unsigned b0 = bpermu(sAl, pha[2]), b1 = bpermu(sAl, pha[3]);
        unsigned b2 = bpermu(sBl, pha[2]), b3 = bpermu(sBl, pha[3]);
        B0.u[0] = lo2 ? a0 : b0; B0.u[1] = lo2 ? a1 : b1;
        B0.u[2] = lo2 ? a2 : b2; B0.u[3] = lo2 ? a3 : b3;
      }
      {
        unsigned a0 = bpermu(sAl, pha[4]), a1 = bpermu(sAl, pha[5]);
        unsigned a2 = bpermu(sBl, pha[4]), a3 = bpermu(sBl, pha[5]);
        unsigned b0 = bpermu(sAl, pha[6]), b1 = bpermu(sAl, pha[7]);
        unsigned b2 = bpermu(sBl, pha[6]), b3 = bpermu(sBl, pha[7]);
        B1.u[0] = lo2 ? a0 : b0; B1.u[1] = lo2 ? a1 : b1;
        B1.u[2] = lo2 ? a2 : b2; B1.u[3] = lo2 ? a3 : b3;
      }
      f32x4 acc3 = {0.f, 0.f, 0.f, 0.f};
      acc3 = MFMA(FR(WS_W2B, 0 * 64 + lane), B0.v, acc3);
      acc3 = MFMA(FR(WS_W2B, 1 * 64 + lane), B1.v, acc3);
      f32x4 s = *(const f32x4*)&bn2b_s[(kblk & 1) * 4];
      f32x4 b = *(const f32x4*)&bn2b_b[(kblk & 1) * 4];
      float v0 = fmaxf(fmaf(acc3[0], s[0], b[0]), 0.f);
      float v1 = fmaxf(fmaf(acc3[1], s[1], b[1]), 0.f);
      float v2 = fmaxf(fmaf(acc3[2], s[2], b[2]), 0.f);
      float v3 = fmaxf(fmaf(acc3[3], s[3], b[3]), 0.f);
      h2p[g][0] = cvtpk(v0, v1);
      h2p[g][1] = cvtpk(v2, v3);
    }
  }

  // ---- route h2 to own row
  unsigned hp0 = 0, hp1 = 0, hp2 = 0, hp3 = 0;
#pragma unroll
  for (int g = 0; g < 4; ++g) {
    unsigned t0 = bpermu(mloc,      h2p[g][0]);
    unsigned t1 = bpermu(mloc,      h2p[g][1]);
    unsigned t2 = bpermu(mloc + 16, h2p[g][0]);
    unsigned t3 = bpermu(mloc + 16, h2p[g][1]);
    const bool mine = (kblk == g);
    hp0 = mine ? t0 : hp0; hp1 = mine ? t1 : hp1;
    hp2 = mine ? t2 : hp2; hp3 = mine ? t3 : hp3;
  }
  float h2r[8];
  h2r[0] = bflo(hp0); h2r[1] = bfhi(hp0); h2r[2] = bflo(hp1); h2r[3] = bfhi(hp1);
  h2r[4] = bflo(hp2); h2r[5] = bfhi(hp2); h2r[6] = bflo(hp3); h2r[7] = bfhi(hp3);

  // ---- W2c + softmax over 16 neighbors (DPP allreduce)
  float h3[8];
#pragma unroll
  for (int b = 0; b < 8; ++b) h3[b] = b2c[b];
#pragma unroll
  for (int m = 0; m < 8; ++m) {
    float r = h2r[m];
#pragma unroll
    for (int b = 0; b < 8; ++b) h3[b] = fmaf(r, W2c[m * 8 + b], h3[b]);
  }
  float wv[8];
#pragma unroll
  for (int b = 0; b < 8; ++b) {
    float mx = h3[b];
    mx = fmaxf(mx, fdpp<0x128>(mx));
    mx = fmaxf(mx, fdpp<0x124>(mx));
    mx = fmaxf(mx, fdpp<0x122>(mx));
    mx = fmaxf(mx, fdpp<0x121>(mx));
    float ex = __expf(h3[b] - mx);
    float s = ex;
    s = s + fdpp<0x128>(s);
    s = s + fdpp<0x124>(s);
    s = s + fdpp<0x122>(s);
    s = s + fdpp<0x121>(s);
    wv[b] = ex * __builtin_amdgcn_rcpf(s);
  }

  // ---- phase 2
  float* xkrow = x_knn + (long long)row * 64;
  float xo[4];
#pragma unroll
  for (int h = 0; h < 2; ++h) {
    float v[32];
    if constexpr (BF) {
      const uint4* y4b = (const uint4*)yv_;
#pragma unroll
      for (int u2 = 0; u2 < 4; ++u2) {
        uint4 yw = y4b[idx * 8 + h * 4 + u2];
        unsigned wd[4] = {yw.x, yw.y, yw.z, yw.w};
#pragma unroll
        for (int half = 0; half < 2; ++half) {
          const int u = u2 * 2 + half;
          float comp[4] = {bflo(wd[half * 2]), bfhi(wd[half * 2]),
                           bflo(wd[half * 2 + 1]), bfhi(wd[half * 2 + 1])};
          f32x4 st;
#pragma unroll
          for (int cc = 0; cc < 4; ++cc) {
            const int c = h * 32 + u * 4 + cc;
            float pe = bp2[c] + q0 * Wp2[c] + q1 * Wp2[64 + c] + q2 * Wp2[128 + c];
            float val = (comp[cc] + pe) * wv[c & 7];
            v[u * 4 + cc] = val;
            st[cc] = val;
          }
          *(f32x4*)(xkrow + h * 32 + u * 4) = st;
        }
      }
    } else {
      const float4* y4 = (const float4*)yv_;
#pragma unroll
      for (int u = 0; u < 8; ++u) {
        float4 yw = y4[idx * 16 + h * 8 + u];
        float comp[4] = {yw.x, yw.y, yw.z, yw.w};
        f32x4 st;
#pragma unroll
        for (int cc = 0; cc < 4; ++cc) {
          const int c = h * 32 + u * 4 + cc;
          float pe = bp2[c] + q0 * Wp2[c] + q1 * Wp2[64 + c] + q2 * Wp2[128 + c];
          float val = (comp[cc] + pe) * wv[c & 7];
          v[u * 4 + cc] = val;
          st[cc] = val;
        }
        *(f32x4*)(xkrow + h * 32 + u * 4) = st;
      }
    }
    // reduce-scatter over the 16-lane group
    const bool b0 = (j & 1), b1 = (j & 2), b2 = (j & 4), b3 = (j & 8);
    float v1[16];
#pragma unroll
    for (int q = 0; q < 16; ++q) {
      float snd = b0 ? v[2 * q] : v[2 * q + 1];
      float rcv = fdpp<0xB1>(snd);
      v1[q] = (b0 ? v[2 * q + 1] : v[2 * q]) + rcv;
    }
    float v2[8];
#pragma unroll
    for (int r = 0; r < 8; ++r) {
      float snd = b1 ? v1[2 * r] : v1[2 * r + 1];
      float rcv = fdpp<0x4E>(snd);
      v2[r] = (b1 ? v1[2 * r + 1] : v1[2 * r]) + rcv;
    }
    float v3[4];
#pragma unroll
    for (int s = 0; s < 4; ++s) {
      float snd = b2 ? v2[2 * s] : v2[2 * s + 1];
      float rcv = fswz<4>(snd);
      v3[s] = (b2 ? v2[2 * s + 1] : v2[2 * s]) + rcv;
    }
    {
      float s0 = b3 ? v3[0] : v3[1];
      float s1 = b3 ? v3[2] : v3[3];
      float r0 = fswz<8>(s0);
      float r1 = fswz<8>(s1);
      xo[2 * h]     = (b3 ? v3[1] : v3[0]) + r0;
      xo[2 * h + 1] = (b3 ? v3[3] : v3[2]) + r1;
    }
  }
#pragma unroll
  for (int g = 0; g < 4; ++g)
    x_out[n * 64 + g * 16 + j] = xo[g];

  if (knn_f) {
    knn_f[row] = (float)idx;
    p_r[row * 3 + 0] = pr0;
    p_r[row * 3 + 1] = pr1;
    p_r[row * 3 + 2] = pr2;
  }
}

// ---------------------------------------------------------------------------
__global__ __launch_bounds__(256) void k_tail(
    const float* __restrict__ p, const int* __restrict__ knn,
    float* __restrict__ knn_f, float* __restrict__ p_r)
{
  int row = blockIdx.x * 256 + threadIdx.x;
  if (row >= NK) return;
  int n = row >> 4;
  int idx = knn[row];
  knn_f[row] = (float)idx;
  p_r[row * 3 + 0] = p[idx * 3 + 0] - p[n * 3 + 0];
  p_r[row * 3 + 1] = p[idx * 3 + 1] - p[n * 3 + 1];
  p_r[row * 3 + 2] = p[idx * 3 + 2] - p[n * 3 + 2];
}

// ---------------------------------------------------------------------------
extern "C" void kernel_launch(void* const* d_in, const int* in_sizes, int n_in,
                              void* d_out, int out_size, void* d_ws, size_t ws_size,
                              hipStream_t stream)
{
  const float* p    = (const float*)d_in[0];
  const float* x    = (const float*)d_in[1];
  const int*   knn  = (const int*)d_in[2];
  const float* W01  = (const float*)d_in[3];
  const float* b01  = (const float*)d_in[4];
  const float* Wbil = (const float*)d_in[5];
  const float* bbil = (const float*)d_in[6];
  const float* Wp1  = (const float*)d_in[7];
  const float* bp1  = (const float*)d_in[8];
  const float* bnps = (const float*)d_in[9];
  const float* bnpb = (const float*)d_in[10];
  const float* Wp2  = (const float*)d_in[11];
  const float* bp2  = (const float*)d_in[12];
  const float* W2a  = (const float*)d_in[13];
  const float* s2a  = (const float*)d_in[14];
  const float* b2a  = (const float*)d_in[15];
  const float* W2b  = (const float*)d_in[16];
  const float* s2b  = (const float*)d_in[17];
  const float* b2b  = (const float*)d_in[18];
  const float* W2c  = (const float*)d_in[19];
  const float* b2c  = (const float*)d_in[20];
  const float* W3   = (const float*)d_in[21];
  const float* b3   = (const float*)d_in[22];

  float* outF  = (float*)d_out;
  float* x_out = outF;                 // [N,64]
  float* x_knn = outF + 6400000;       // [N,16,64]
  float* knn_f = outF + 108800000;     // [N,16]
  float* p_r   = outF + 110400000;     // [N,16,3]
  short* wsf   = (short*)d_ws;

  k_prep<<<1, 256, 0, stream>>>(W01, b01, Wbil, W2a, W2b, Wp2, bp2, wsf);

  if (ws_size >= (size_t)WS_NEED) {
    unsigned* xbf = (unsigned*)((char*)d_ws + WS_XBF);
    short*    ybf = (short*)((char*)d_ws + WS_YBF);
    k_cvt<<<6250, 256, 0, stream>>>(x, xbf);
    k_xw3<true><<<25000, 256, 0, stream>>>(x, W3, b3, ybf);
    k_main<true><<<6250, 256, 0, stream>>>(p, x, knn, wsf, Wp1, bp1, bnps, bnpb,
                                           bbil, s2a, b2a, s2b, b2b, W2c, b2c,
                                           Wp2, bp2, ybf, xbf, x_out, x_knn,
                                           knn_f, p_r);
  } else {
    float* y = knn_f;                  // reuse tail for x@W3+b3 (f32)
    k_xw3<false><<<25000, 256, 0, stream>>>(x, W3, b3, y);
    k_main<false><<<6250, 256, 0, stream>>>(p, x, knn, wsf, Wp1, bp1, bnps, bnpb,
                                            bbil, s2a, b2a, s2b, b2b, W2c, b2c,
                                            Wp2, bp2, y, nullptr, x_out, x_knn,
                                            (float*)nullptr, (float*)nullptr);
    k_tail<<<6250, 256, 0, stream>>>(p, knn, knn_f, p_r);
  }
}